// Round 1
// baseline (661.544 us; speedup 1.0000x reference)
//
#include <hip/hip_runtime.h>

#define HID 128

// ---------- float <-> orderable-uint encoding for atomic max ----------
__device__ __forceinline__ unsigned enc_f32(float f) {
    unsigned u = __float_as_uint(f);
    return (u & 0x80000000u) ? ~u : (u | 0x80000000u);
}
__device__ __forceinline__ float dec_f32(unsigned e) {
    unsigned u = (e & 0x80000000u) ? (e & 0x7fffffffu) : ~e;
    return __uint_as_float(u);
}

// ---------- generic 128-wide SGEMM: C[r][c] = ep(A[r][:]@B[:][c] + Add + bias) ----------
// A: M x 128 (lda), B: 128 x 128 row-major, C: M x (ldc) at given pointer.
__global__ __launch_bounds__(256)
void gemm128(const float* __restrict__ A, int lda, int M,
             const float* __restrict__ B,
             const float* __restrict__ Add, int ldadd,   // may be null
             const float* __restrict__ bias,             // may be null
             float* __restrict__ C, int ldc, int relu)
{
    __shared__ float As[8][128];   // [k][m]
    __shared__ float Bs[8][128];   // [k][n]
    const int tid = threadIdx.x;
    const int row0 = blockIdx.x * 128;
    const int tx = tid & 15;       // 16 col-groups of 8
    const int ty = tid >> 4;       // 16 row-groups of 8

    float acc[8][8];
#pragma unroll
    for (int i = 0; i < 8; i++)
#pragma unroll
        for (int j = 0; j < 8; j++) acc[i][j] = 0.f;

    const int ar = tid >> 1;            // 0..127 (row within tile)
    const int ac = (tid & 1) * 4;       // 0 or 4 (k within 8-chunk)
    const int br = tid >> 5;            // 0..7   (k row)
    const int bc = (tid & 31) * 4;      // 0..124 (col)

    for (int k0 = 0; k0 < 128; k0 += 8) {
        float4 av = make_float4(0.f, 0.f, 0.f, 0.f);
        const int arow = row0 + ar;
        if (arow < M) av = *(const float4*)&A[(size_t)arow * lda + k0 + ac];
        float4 bv = *(const float4*)&B[(br + k0) * 128 + bc];

        __syncthreads();
        As[ac + 0][ar] = av.x; As[ac + 1][ar] = av.y;
        As[ac + 2][ar] = av.z; As[ac + 3][ar] = av.w;
        *(float4*)&Bs[br][bc] = bv;
        __syncthreads();

#pragma unroll
        for (int kk = 0; kk < 8; kk++) {
            float a[8], b[8];
#pragma unroll
            for (int i = 0; i < 8; i++) a[i] = As[kk][ty * 8 + i];
#pragma unroll
            for (int j = 0; j < 8; j++) b[j] = Bs[kk][tx * 8 + j];
#pragma unroll
            for (int i = 0; i < 8; i++)
#pragma unroll
                for (int j = 0; j < 8; j++)
                    acc[i][j] = fmaf(a[i], b[j], acc[i][j]);
        }
    }

    // epilogue
#pragma unroll
    for (int i = 0; i < 8; i++) {
        const int r = row0 + ty * 8 + i;
        if (r >= M) break;
#pragma unroll
        for (int j = 0; j < 8; j++) {
            const int c = tx * 8 + j;
            float v = acc[i][j];
            if (Add)  v += Add[(size_t)r * ldadd + c];
            if (bias) v += bias[c];
            if (relu) v = fmaxf(v, 0.f);
            C[(size_t)r * ldc + c] = v;
        }
    }
}

// ---------- edge phase: aggenc[dst][h] = max over edges of enc(zWs[src][h] + w*ww[h]) ----------
__global__ __launch_bounds__(256)
void edge_max_kernel(const float* __restrict__ zWs, int ldP,
                     const float* __restrict__ ew,
                     const int* __restrict__ esrc,
                     const int* __restrict__ edst,
                     const float* __restrict__ ww,
                     unsigned* __restrict__ aggenc,
                     int nE)
{
    const int idx = blockIdx.x * blockDim.x + threadIdx.x;
    const int e = idx >> 7;
    const int h = idx & 127;
    if (e >= nE) return;
    const int s = esrc[e];
    const int d = edst[e];
    const float w = ew[e];
    const float val = zWs[(size_t)s * ldP + h] + w * ww[h];
    atomicMax(&aggenc[(size_t)d * HID + h], enc_f32(val));
}

// ---------- finalize: agg = (touched) ? zWd + bm + max : 0 ----------
__global__ __launch_bounds__(256)
void finalize_agg(const float* __restrict__ P, int ldP,
                  const float* __restrict__ bm,
                  const unsigned* __restrict__ aggenc,
                  float* __restrict__ agg, int total)
{
    const int idx = blockIdx.x * blockDim.x + threadIdx.x;
    if (idx >= total) return;
    const int n = idx >> 7;
    const int h = idx & 127;
    const unsigned e = aggenc[idx];
    agg[idx] = (e == 0u) ? 0.f : (P[(size_t)n * ldP + h] + bm[h] + dec_f32(e));
}

extern "C" void kernel_launch(void* const* d_in, const int* in_sizes, int n_in,
                              void* d_out, int out_size, void* d_ws, size_t ws_size,
                              hipStream_t stream) {
    const float* z    = (const float*)d_in[0];
    const float* ew   = (const float*)d_in[1];
    const int*   esrc = (const int*)d_in[2];
    const int*   edst = (const int*)d_in[3];
    const float* Wm   = (const float*)d_in[4];
    const float* bm   = (const float*)d_in[5];
    const float* W1   = (const float*)d_in[6];
    const float* b1   = (const float*)d_in[7];
    const float* W2   = (const float*)d_in[8];
    const float* b2   = (const float*)d_in[9];
    float* out = (float*)d_out;

    const int N = in_sizes[0] / HID;   // 50000
    const int E = in_sizes[1];         // 800000

    // workspace layout
    float*    P      = (float*)d_ws;                          // N x 384: [zWd | zWs | zW1a]
    unsigned* aggenc = (unsigned*)(P + (size_t)N * 384);      // N x 128
    float*    agg    = (float*)(aggenc + (size_t)N * HID);    // N x 128
    float*    hidden = agg + (size_t)N * HID;                 // N x 128

    hipMemsetAsync(aggenc, 0, (size_t)N * HID * sizeof(unsigned), stream);

    const int gblocks = (N + 127) / 128;
    // P[:,0:128] = z @ Wd ; P[:,128:256] = z @ Ws ; P[:,256:384] = z @ W1a
    gemm128<<<gblocks, 256, 0, stream>>>(z, HID, N, Wm,             nullptr, 0, nullptr, P,       384, 0);
    gemm128<<<gblocks, 256, 0, stream>>>(z, HID, N, Wm + 128 * HID, nullptr, 0, nullptr, P + 128, 384, 0);
    gemm128<<<gblocks, 256, 0, stream>>>(z, HID, N, W1,             nullptr, 0, nullptr, P + 256, 384, 0);

    // segment max over edges (encoded atomics)
    {
        const int total = E * HID;               // 102.4M < 2^31
        const int blocks = (total + 255) / 256;
        edge_max_kernel<<<blocks, 256, 0, stream>>>(P + 128, 384, ew, esrc, edst,
                                                    Wm + 256 * HID, aggenc, E);
    }

    // agg = where(deg>0, zWd + bm + max, 0)
    {
        const int total = N * HID;
        finalize_agg<<<(total + 255) / 256, 256, 0, stream>>>(P, 384, bm, aggenc, agg, total);
    }

    // hidden = relu(zW1a + agg @ W1b + b1)
    gemm128<<<gblocks, 256, 0, stream>>>(agg, HID, N, W1 + 128 * HID, P + 256, 384, b1, hidden, HID, 1);
    // out = hidden @ W2 + b2
    gemm128<<<gblocks, 256, 0, stream>>>(hidden, HID, N, W2, nullptr, 0, b2, out, HID, 0);
}

// Round 2
// 617.107 us; speedup vs baseline: 1.0720x; 1.0720x over previous
//
#include <hip/hip_runtime.h>

#define HID 128

// ---------- generic 128-wide SGEMM: C[r][c] = ep(A[r][:]@B[:][c] + Add + bias) ----------
__global__ __launch_bounds__(256)
void gemm128(const float* __restrict__ A, int lda, int M,
             const float* __restrict__ B,
             const float* __restrict__ Add, int ldadd,   // may be null
             const float* __restrict__ bias,             // may be null
             float* __restrict__ C, int ldc, int relu)
{
    __shared__ float As[8][128];   // [k][m]
    __shared__ float Bs[8][128];   // [k][n]
    const int tid = threadIdx.x;
    const int row0 = blockIdx.x * 128;
    const int tx = tid & 15;
    const int ty = tid >> 4;

    float acc[8][8];
#pragma unroll
    for (int i = 0; i < 8; i++)
#pragma unroll
        for (int j = 0; j < 8; j++) acc[i][j] = 0.f;

    const int ar = tid >> 1;
    const int ac = (tid & 1) * 4;
    const int br = tid >> 5;
    const int bc = (tid & 31) * 4;

    for (int k0 = 0; k0 < 128; k0 += 8) {
        float4 av = make_float4(0.f, 0.f, 0.f, 0.f);
        const int arow = row0 + ar;
        if (arow < M) av = *(const float4*)&A[(size_t)arow * lda + k0 + ac];
        float4 bv = *(const float4*)&B[(br + k0) * 128 + bc];

        __syncthreads();
        As[ac + 0][ar] = av.x; As[ac + 1][ar] = av.y;
        As[ac + 2][ar] = av.z; As[ac + 3][ar] = av.w;
        *(float4*)&Bs[br][bc] = bv;
        __syncthreads();

#pragma unroll
        for (int kk = 0; kk < 8; kk++) {
            float a[8], b[8];
#pragma unroll
            for (int i = 0; i < 8; i++) a[i] = As[kk][ty * 8 + i];
#pragma unroll
            for (int j = 0; j < 8; j++) b[j] = Bs[kk][tx * 8 + j];
#pragma unroll
            for (int i = 0; i < 8; i++)
#pragma unroll
                for (int j = 0; j < 8; j++)
                    acc[i][j] = fmaf(a[i], b[j], acc[i][j]);
        }
    }

#pragma unroll
    for (int i = 0; i < 8; i++) {
        const int r = row0 + ty * 8 + i;
        if (r >= M) break;
#pragma unroll
        for (int j = 0; j < 8; j++) {
            const int c = tx * 8 + j;
            float v = acc[i][j];
            if (Add)  v += Add[(size_t)r * ldadd + c];
            if (bias) v += bias[c];
            if (relu) v = fmaxf(v, 0.f);
            C[(size_t)r * ldc + c] = v;
        }
    }
}

// ---------- counting-sort phase ----------
__global__ __launch_bounds__(256)
void hist_kernel(const int* __restrict__ edst, int* __restrict__ deg, int E)
{
    const int e = blockIdx.x * blockDim.x + threadIdx.x;
    if (e < E) atomicAdd(&deg[edst[e]], 1);
}

// one-block exclusive scan over N counts -> offsets[0..N], cursor copy
__global__ __launch_bounds__(1024)
void scan_kernel(const int* __restrict__ deg, int* __restrict__ offsets,
                 int* __restrict__ cursor, int N)
{
    __shared__ int sums[1024];
    const int t = threadIdx.x;
    const int chunk = (N + 1023) >> 10;
    const int lo = t * chunk;
    const int hi = min(lo + chunk, N);
    int s = 0;
    for (int i = lo; i < hi; i++) s += deg[i];
    sums[t] = s;
    __syncthreads();
    for (int d = 1; d < 1024; d <<= 1) {
        int add = (t >= d) ? sums[t - d] : 0;
        __syncthreads();
        sums[t] += add;
        __syncthreads();
    }
    int run = sums[t] - s;   // exclusive prefix
    for (int i = lo; i < hi; i++) {
        offsets[i] = run;
        cursor[i]  = run;
        run += deg[i];
    }
    if (lo < N && hi == N) offsets[N] = run;
}

__global__ __launch_bounds__(256)
void scatter_kernel(const int* __restrict__ esrc, const int* __restrict__ edst,
                    const float* __restrict__ ew,
                    int* __restrict__ cursor,
                    int* __restrict__ s_src, float* __restrict__ s_w, int E)
{
    const int e = blockIdx.x * blockDim.x + threadIdx.x;
    if (e >= E) return;
    const int d = edst[e];
    const int pos = atomicAdd(&cursor[d], 1);
    s_src[pos] = esrc[e];
    s_w[pos]   = ew[e];
}

// ---------- per-node segmented max (no atomics), fused finalize ----------
// 256 threads = 2 nodes; thread owns one h of one node.
__global__ __launch_bounds__(256)
void aggregate_kernel(const float* __restrict__ P, // N x 384: [zWd | zWs | zW1a]
                      const float* __restrict__ bm,
                      const float* __restrict__ ww,
                      const int* __restrict__ offsets,
                      const int* __restrict__ s_src,
                      const float* __restrict__ s_w,
                      float* __restrict__ agg, int N)
{
    const int t = threadIdx.x;
    const int h = t & 127;
    const int n = blockIdx.x * 2 + (t >> 7);
    if (n >= N) return;
    const int start = offsets[n];
    const int end   = offsets[n + 1];
    const float wwh = ww[h];
    float acc = -INFINITY;
    int e = start;
    for (; e + 1 < end; e += 2) {
        const int   s0 = s_src[e],   s1 = s_src[e + 1];
        const float w0 = s_w[e],     w1 = s_w[e + 1];
        const float v0 = fmaf(w0, wwh, P[(size_t)s0 * 384 + 128 + h]);
        const float v1 = fmaf(w1, wwh, P[(size_t)s1 * 384 + 128 + h]);
        acc = fmaxf(acc, fmaxf(v0, v1));
    }
    if (e < end) {
        const int   s0 = s_src[e];
        const float w0 = s_w[e];
        acc = fmaxf(acc, fmaf(w0, wwh, P[(size_t)s0 * 384 + 128 + h]));
    }
    agg[(size_t)n * HID + h] =
        (end > start) ? (P[(size_t)n * 384 + h] + bm[h] + acc) : 0.f;
}

extern "C" void kernel_launch(void* const* d_in, const int* in_sizes, int n_in,
                              void* d_out, int out_size, void* d_ws, size_t ws_size,
                              hipStream_t stream) {
    const float* z    = (const float*)d_in[0];
    const float* ew   = (const float*)d_in[1];
    const int*   esrc = (const int*)d_in[2];
    const int*   edst = (const int*)d_in[3];
    const float* Wm   = (const float*)d_in[4];
    const float* bm   = (const float*)d_in[5];
    const float* W1   = (const float*)d_in[6];
    const float* b1   = (const float*)d_in[7];
    const float* W2   = (const float*)d_in[8];
    const float* b2   = (const float*)d_in[9];
    float* out = (float*)d_out;

    const int N = in_sizes[0] / HID;   // 50000
    const int E = in_sizes[1];         // 800000

    // workspace layout (all 4B elements)
    float* P       = (float*)d_ws;                      // N x 384: [zWd | zWs | zW1a]
    float* agg     = P + (size_t)N * 384;               // N x 128
    float* hidden  = agg + (size_t)N * HID;             // N x 128
    int*   deg     = (int*)(hidden + (size_t)N * HID);  // N
    int*   offsets = deg + N;                           // N + 1
    int*   cursor  = offsets + N + 1;                   // N
    int*   s_src   = cursor + N;                        // E
    float* s_w     = (float*)(s_src + E);               // E

    // --- counting sort of edges by dst ---
    hipMemsetAsync(deg, 0, (size_t)N * sizeof(int), stream);
    hist_kernel<<<(E + 255) / 256, 256, 0, stream>>>(edst, deg, E);
    scan_kernel<<<1, 1024, 0, stream>>>(deg, offsets, cursor, N);
    scatter_kernel<<<(E + 255) / 256, 256, 0, stream>>>(esrc, edst, ew, cursor, s_src, s_w, E);

    // --- node-side projections: P = z @ [Wd | Ws | W1a] ---
    const int gblocks = (N + 127) / 128;
    gemm128<<<gblocks, 256, 0, stream>>>(z, HID, N, Wm,             nullptr, 0, nullptr, P,       384, 0);
    gemm128<<<gblocks, 256, 0, stream>>>(z, HID, N, Wm + 128 * HID, nullptr, 0, nullptr, P + 128, 384, 0);
    gemm128<<<gblocks, 256, 0, stream>>>(z, HID, N, W1,             nullptr, 0, nullptr, P + 256, 384, 0);

    // --- segmented max + finalize (no atomics) ---
    aggregate_kernel<<<(N + 1) / 2, 256, 0, stream>>>(P, bm, Wm + 256 * HID,
                                                      offsets, s_src, s_w, agg, N);

    // hidden = relu(zW1a + agg @ W1b + b1)
    gemm128<<<gblocks, 256, 0, stream>>>(agg, HID, N, W1 + 128 * HID, P + 256, 384, b1, hidden, HID, 1);
    // out = hidden @ W2 + b2
    gemm128<<<gblocks, 256, 0, stream>>>(hidden, HID, N, W2, nullptr, 0, b2, out, HID, 0);
}

// Round 3
// 347.143 us; speedup vs baseline: 1.9057x; 1.7777x over previous
//
#include <hip/hip_runtime.h>
#include <hip/hip_bf16.h>

#define HID 128

typedef short bf16x8 __attribute__((ext_vector_type(8)));
typedef float f32x4  __attribute__((ext_vector_type(4)));
typedef unsigned short u16;

__device__ __forceinline__ u16 f2bf(float f) {
    __hip_bfloat16 h = __float2bfloat16(f);
    return *reinterpret_cast<u16*>(&h);
}

// =====================================================================
// bf16 MFMA GEMM, M x 128(col-slice) x K=128.  No LDS: B slice (32 KB)
// is L1/L2-resident; A read once, coalesced (64B segments per frag-load).
// A: [Mp][128] bf16 row-major.  Bt: [ncols][128] bf16 (n-major, k contig).
// Block = 256 thr = 4 waves; tile 64 rows x 128 cols; wave = 32x64.
// =====================================================================
__global__ __launch_bounds__(256)
void gemm_mfma(const u16* __restrict__ A,
               const u16* __restrict__ Bt,
               const float* __restrict__ Add, int ldadd,  // may be null
               const float* __restrict__ bias,            // may be null
               float* __restrict__ Cf,                    // fp32 out (or null)
               u16* __restrict__ Cb,                      // bf16 out (or null)
               int ldc, int Mstore, int relu)
{
    const int row0 = blockIdx.x * 64;
    const int col0 = blockIdx.y * 128;
    const int tid  = threadIdx.x;
    const int wv = tid >> 6, lane = tid & 63;
    const int wy = wv & 1, wx = wv >> 1;
    const int q = lane >> 4, n = lane & 15;

    // A-frag: A[m=lane&15][k=q*8+j]; B-frag: B[k=q*8+j][n=lane&15] (Bt n-major)
    const u16* pA = A  + (size_t)(row0 + wy * 32 + n) * 128 + q * 8;
    const u16* pB = Bt + (size_t)(col0 + wx * 64 + n) * 128 + q * 8;

    f32x4 acc[2][4];
#pragma unroll
    for (int i = 0; i < 2; i++)
#pragma unroll
        for (int j = 0; j < 4; j++) acc[i][j] = f32x4{0.f, 0.f, 0.f, 0.f};

#pragma unroll
    for (int kk = 0; kk < 128; kk += 32) {
        bf16x8 a0 = *(const bf16x8*)(pA + kk);
        bf16x8 a1 = *(const bf16x8*)(pA + 16 * 128 + kk);
        bf16x8 b0 = *(const bf16x8*)(pB + kk);
        bf16x8 b1 = *(const bf16x8*)(pB + 16 * 128 + kk);
        bf16x8 b2 = *(const bf16x8*)(pB + 32 * 128 + kk);
        bf16x8 b3 = *(const bf16x8*)(pB + 48 * 128 + kk);
        acc[0][0] = __builtin_amdgcn_mfma_f32_16x16x32_bf16(a0, b0, acc[0][0], 0, 0, 0);
        acc[0][1] = __builtin_amdgcn_mfma_f32_16x16x32_bf16(a0, b1, acc[0][1], 0, 0, 0);
        acc[0][2] = __builtin_amdgcn_mfma_f32_16x16x32_bf16(a0, b2, acc[0][2], 0, 0, 0);
        acc[0][3] = __builtin_amdgcn_mfma_f32_16x16x32_bf16(a0, b3, acc[0][3], 0, 0, 0);
        acc[1][0] = __builtin_amdgcn_mfma_f32_16x16x32_bf16(a1, b0, acc[1][0], 0, 0, 0);
        acc[1][1] = __builtin_amdgcn_mfma_f32_16x16x32_bf16(a1, b1, acc[1][1], 0, 0, 0);
        acc[1][2] = __builtin_amdgcn_mfma_f32_16x16x32_bf16(a1, b2, acc[1][2], 0, 0, 0);
        acc[1][3] = __builtin_amdgcn_mfma_f32_16x16x32_bf16(a1, b3, acc[1][3], 0, 0, 0);
    }

    // C/D layout: col = lane&15, row = q*4 + reg  (m89-verified)
#pragma unroll
    for (int mi = 0; mi < 2; mi++) {
#pragma unroll
        for (int ni = 0; ni < 4; ni++) {
            const int rbase = row0 + wy * 32 + mi * 16 + q * 4;
            const int c = col0 + wx * 64 + ni * 16 + n;
#pragma unroll
            for (int r = 0; r < 4; r++) {
                const int rr = rbase + r;
                if (rr >= Mstore) continue;
                float v = acc[mi][ni][r];
                if (Add)  v += Add[(size_t)rr * ldadd + c];
                if (bias) v += bias[c];
                if (relu) v = fmaxf(v, 0.f);
                if (Cf) Cf[(size_t)rr * ldc + c] = v;
                else    Cb[(size_t)rr * ldc + c] = f2bf(v);
            }
        }
    }
}

// ---------- prep: cast z to bf16 (pad rows -> 0) ----------
__global__ __launch_bounds__(256)
void cast_z(const float* __restrict__ z, u16* __restrict__ zb, int N, int Mp)
{
    const int idx = (blockIdx.x * 256 + threadIdx.x) * 4;
    if (idx >= Mp * 128) return;
    const int row = idx >> 7;
    ushort4 u;
    if (row < N) {
        const float4 v = *(const float4*)&z[idx];
        u.x = f2bf(v.x); u.y = f2bf(v.y); u.z = f2bf(v.z); u.w = f2bf(v.w);
    } else {
        u.x = 0; u.y = 0; u.z = 0; u.w = 0;
    }
    *(ushort4*)&zb[idx] = u;
}

// ---------- prep: transpose+cast 5 weight mats to [n][k] bf16 ----------
// Btw rows: 0-127 Wd^T | 128-255 Ws^T | 256-383 W1a^T | 384-511 W1b^T | 512-639 W2^T
__global__ __launch_bounds__(256)
void prep_weights(const float* __restrict__ Wm, const float* __restrict__ W1,
                  const float* __restrict__ W2, u16* __restrict__ Btw)
{
    const int idx = blockIdx.x * 256 + threadIdx.x;
    if (idx >= 640 * 128) return;
    const int nn = idx >> 7, k = idx & 127;
    float v;
    if      (nn < 128) v = Wm[k * 128 + nn];
    else if (nn < 256) v = Wm[(128 + k) * 128 + (nn - 128)];
    else if (nn < 384) v = W1[k * 128 + (nn - 256)];
    else if (nn < 512) v = W1[(128 + k) * 128 + (nn - 384)];
    else               v = W2[k * 128 + (nn - 512)];
    Btw[idx] = f2bf(v);
}

// ---------- counting sort ----------
__global__ __launch_bounds__(256)
void hist_kernel(const int* __restrict__ edst, int* __restrict__ deg, int E)
{
    const int e = blockIdx.x * blockDim.x + threadIdx.x;
    if (e < E) atomicAdd(&deg[edst[e]], 1);
}

__global__ __launch_bounds__(256)
void scan_bsum(const int* __restrict__ deg, int* __restrict__ bsum, int N)
{
    __shared__ int red[4];
    const int t = threadIdx.x;
    const int base = blockIdx.x * 1024 + t * 4;
    int s = 0;
#pragma unroll
    for (int j = 0; j < 4; j++) { int i = base + j; if (i < N) s += deg[i]; }
#pragma unroll
    for (int off = 32; off > 0; off >>= 1) s += __shfl_down(s, off);
    if ((t & 63) == 0) red[t >> 6] = s;
    __syncthreads();
    if (t == 0) bsum[blockIdx.x] = red[0] + red[1] + red[2] + red[3];
}

__global__ void scan_boff(const int* __restrict__ bsum, int* __restrict__ boff, int nb)
{
    if (threadIdx.x == 0) {
        int run = 0;
        for (int i = 0; i < nb; i++) { boff[i] = run; run += bsum[i]; }
    }
}

__global__ __launch_bounds__(256)
void scan_final(const int* __restrict__ deg, const int* __restrict__ boff,
                int* __restrict__ offsets, int* __restrict__ cursor, int N, int E)
{
    __shared__ int ps[256];
    const int t = threadIdx.x;
    const int base = blockIdx.x * 1024 + t * 4;
    int d[4]; int s = 0;
#pragma unroll
    for (int j = 0; j < 4; j++) { int i = base + j; d[j] = (i < N) ? deg[i] : 0; s += d[j]; }
    ps[t] = s;
    __syncthreads();
    for (int off = 1; off < 256; off <<= 1) {
        int add = (t >= off) ? ps[t - off] : 0;
        __syncthreads();
        ps[t] += add;
        __syncthreads();
    }
    int run = ps[t] - s + boff[blockIdx.x];
#pragma unroll
    for (int j = 0; j < 4; j++) {
        int i = base + j;
        if (i < N) { offsets[i] = run; cursor[i] = run; }
        run += d[j];
    }
    if (blockIdx.x == 0 && t == 0) offsets[N] = E;
}

__global__ __launch_bounds__(256)
void scatter_kernel(const int* __restrict__ esrc, const int* __restrict__ edst,
                    const float* __restrict__ ew,
                    int* __restrict__ cursor,
                    int* __restrict__ s_src, float* __restrict__ s_w, int E)
{
    const int e = blockIdx.x * blockDim.x + threadIdx.x;
    if (e >= E) return;
    const int d = edst[e];
    const int pos = atomicAdd(&cursor[d], 1);
    s_src[pos] = esrc[e];
    s_w[pos]   = ew[e];
}

// ---------- per-node segmented max + finalize, bf16 out ----------
__global__ __launch_bounds__(256)
void aggregate_kernel(const float* __restrict__ P,   // Mp x 384: [zWd | zWs | zW1a]
                      const float* __restrict__ bm,
                      const float* __restrict__ ww,
                      const int* __restrict__ offsets,
                      const int* __restrict__ s_src,
                      const float* __restrict__ s_w,
                      u16* __restrict__ aggb, int N, int Mp)
{
    const int t = threadIdx.x;
    const int h = t & 127;
    const int nd = blockIdx.x * 2 + (t >> 7);
    if (nd >= Mp) return;
    if (nd >= N) { aggb[(size_t)nd * HID + h] = 0; return; }
    const int start = offsets[nd];
    const int end   = offsets[nd + 1];
    const float wwh = ww[h];
    float acc = -INFINITY;
    int e = start;
    for (; e + 1 < end; e += 2) {
        const int   s0 = s_src[e],   s1 = s_src[e + 1];
        const float w0 = s_w[e],     w1 = s_w[e + 1];
        const float v0 = fmaf(w0, wwh, P[(size_t)s0 * 384 + 128 + h]);
        const float v1 = fmaf(w1, wwh, P[(size_t)s1 * 384 + 128 + h]);
        acc = fmaxf(acc, fmaxf(v0, v1));
    }
    if (e < end) {
        acc = fmaxf(acc, fmaf(s_w[e], wwh, P[(size_t)s_src[e] * 384 + 128 + h]));
    }
    const float res = (end > start) ? (P[(size_t)nd * 384 + h] + bm[h] + acc) : 0.f;
    aggb[(size_t)nd * HID + h] = f2bf(res);
}

extern "C" void kernel_launch(void* const* d_in, const int* in_sizes, int n_in,
                              void* d_out, int out_size, void* d_ws, size_t ws_size,
                              hipStream_t stream) {
    const float* z    = (const float*)d_in[0];
    const float* ew   = (const float*)d_in[1];
    const int*   esrc = (const int*)d_in[2];
    const int*   edst = (const int*)d_in[3];
    const float* Wm   = (const float*)d_in[4];
    const float* bm   = (const float*)d_in[5];
    const float* W1   = (const float*)d_in[6];
    const float* b1   = (const float*)d_in[7];
    const float* W2   = (const float*)d_in[8];
    const float* b2   = (const float*)d_in[9];
    float* out = (float*)d_out;

    const int N  = in_sizes[0] / HID;          // 50000
    const int E  = in_sizes[1];                // 800000
    const int Mp = ((N + 63) / 64) * 64;       // padded rows (50048)

    // workspace layout
    char* w = (char*)d_ws;
    float* P       = (float*)w;  w += (size_t)Mp * 384 * 4;   // fp32 [zWd|zWs|zW1a]
    u16*  zb       = (u16*)w;    w += (size_t)Mp * 128 * 2;
    u16*  aggb     = (u16*)w;    w += (size_t)Mp * 128 * 2;
    u16*  hiddenb  = (u16*)w;    w += (size_t)Mp * 128 * 2;
    u16*  Btw      = (u16*)w;    w += (size_t)640 * 128 * 2;
    int*  deg      = (int*)w;    w += (size_t)(N + 64) * 4;
    int*  offsets  = (int*)w;    w += (size_t)(N + 64) * 4;
    int*  cursor   = (int*)w;    w += (size_t)(N + 64) * 4;
    int*  bsum     = (int*)w;    w += 256;
    int*  boff     = (int*)w;    w += 256;
    int*  s_src    = (int*)w;    w += (size_t)E * 4;
    float* s_w     = (float*)w;  w += (size_t)E * 4;

    const int nb = (N + 1023) / 1024;          // 49 scan blocks

    // --- counting sort of edges by dst (parallel scan) ---
    hipMemsetAsync(deg, 0, (size_t)N * sizeof(int), stream);
    hist_kernel<<<(E + 255) / 256, 256, 0, stream>>>(edst, deg, E);
    scan_bsum<<<nb, 256, 0, stream>>>(deg, bsum, N);
    scan_boff<<<1, 64, 0, stream>>>(bsum, boff, nb);
    scan_final<<<nb, 256, 0, stream>>>(deg, boff, offsets, cursor, N, E);
    scatter_kernel<<<(E + 255) / 256, 256, 0, stream>>>(esrc, edst, ew, cursor, s_src, s_w, E);

    // --- bf16 prep ---
    cast_z<<<(Mp * 128 / 4 + 255) / 256, 256, 0, stream>>>(z, zb, N, Mp);
    prep_weights<<<(640 * 128 + 255) / 256, 256, 0, stream>>>(Wm, W1, W2, Btw);

    // --- P = z @ [Wd | Ws | W1a]  (one MFMA GEMM, 3 col-slices) ---
    gemm_mfma<<<dim3(Mp / 64, 3), 256, 0, stream>>>(zb, Btw, nullptr, 0, nullptr,
                                                    P, nullptr, 384, Mp, 0);

    // --- segmented max + finalize -> aggb (bf16) ---
    aggregate_kernel<<<(Mp + 1) / 2, 256, 0, stream>>>(P, bm, Wm + 256 * 128,
                                                       offsets, s_src, s_w, aggb, N, Mp);

    // --- hidden = relu(agg @ W1b + zW1a + b1) -> bf16 ---
    gemm_mfma<<<dim3(Mp / 64, 1), 256, 0, stream>>>(aggb, Btw + 384 * 128, P + 256, 384,
                                                    b1, nullptr, hiddenb, 128, Mp, 1);

    // --- out = hidden @ W2 + b2 (fp32) ---
    gemm_mfma<<<dim3(Mp / 64, 1), 256, 0, stream>>>(hiddenb, Btw + 512 * 128, nullptr, 0,
                                                    b2, out, nullptr, 128, N, 0);
}

// Round 4
// 323.925 us; speedup vs baseline: 2.0423x; 1.0717x over previous
//
#include <hip/hip_runtime.h>
#include <hip/hip_bf16.h>

#define HID 128

typedef short bf16x8 __attribute__((ext_vector_type(8)));
typedef float f32x4  __attribute__((ext_vector_type(4)));
typedef unsigned short u16;

__device__ __forceinline__ u16 f2bf(float f) {
    __hip_bfloat16 h = __float2bfloat16(f);
    return *reinterpret_cast<u16*>(&h);
}
__device__ __forceinline__ float bf2f(u16 x) {
    unsigned u = ((unsigned)x) << 16;
    return __uint_as_float(u);
}

// =====================================================================
// bf16 MFMA GEMM, M x 128(col-slice) x K=128.  No LDS: B slice (32 KB)
// is L1/L2-resident. A: [Mp][128] bf16. Bt: [ncols][128] bf16 (n-major).
// Block = 256 thr = 4 waves; tile 64 rows x 128 cols; wave = 32x64.
// Add (optional) is bf16 with leading dim ldadd. Out: fp32 Cf or bf16 Cb.
// =====================================================================
__global__ __launch_bounds__(256)
void gemm_mfma(const u16* __restrict__ A,
               const u16* __restrict__ Bt,
               const u16* __restrict__ Add, int ldadd,   // may be null
               const float* __restrict__ bias,           // may be null
               float* __restrict__ Cf,                   // fp32 out (or null)
               u16* __restrict__ Cb,                     // bf16 out (or null)
               int ldc, int Mstore, int relu)
{
    const int row0 = blockIdx.x * 64;
    const int col0 = blockIdx.y * 128;
    const int tid  = threadIdx.x;
    const int wv = tid >> 6, lane = tid & 63;
    const int wy = wv & 1, wx = wv >> 1;
    const int q = lane >> 4, n = lane & 15;

    const u16* pA = A  + (size_t)(row0 + wy * 32 + n) * 128 + q * 8;
    const u16* pB = Bt + (size_t)(col0 + wx * 64 + n) * 128 + q * 8;

    f32x4 acc[2][4];
#pragma unroll
    for (int i = 0; i < 2; i++)
#pragma unroll
        for (int j = 0; j < 4; j++) acc[i][j] = f32x4{0.f, 0.f, 0.f, 0.f};

#pragma unroll
    for (int kk = 0; kk < 128; kk += 32) {
        bf16x8 a0 = *(const bf16x8*)(pA + kk);
        bf16x8 a1 = *(const bf16x8*)(pA + 16 * 128 + kk);
        bf16x8 b0 = *(const bf16x8*)(pB + kk);
        bf16x8 b1 = *(const bf16x8*)(pB + 16 * 128 + kk);
        bf16x8 b2 = *(const bf16x8*)(pB + 32 * 128 + kk);
        bf16x8 b3 = *(const bf16x8*)(pB + 48 * 128 + kk);
        acc[0][0] = __builtin_amdgcn_mfma_f32_16x16x32_bf16(a0, b0, acc[0][0], 0, 0, 0);
        acc[0][1] = __builtin_amdgcn_mfma_f32_16x16x32_bf16(a0, b1, acc[0][1], 0, 0, 0);
        acc[0][2] = __builtin_amdgcn_mfma_f32_16x16x32_bf16(a0, b2, acc[0][2], 0, 0, 0);
        acc[0][3] = __builtin_amdgcn_mfma_f32_16x16x32_bf16(a0, b3, acc[0][3], 0, 0, 0);
        acc[1][0] = __builtin_amdgcn_mfma_f32_16x16x32_bf16(a1, b0, acc[1][0], 0, 0, 0);
        acc[1][1] = __builtin_amdgcn_mfma_f32_16x16x32_bf16(a1, b1, acc[1][1], 0, 0, 0);
        acc[1][2] = __builtin_amdgcn_mfma_f32_16x16x32_bf16(a1, b2, acc[1][2], 0, 0, 0);
        acc[1][3] = __builtin_amdgcn_mfma_f32_16x16x32_bf16(a1, b3, acc[1][3], 0, 0, 0);
    }

    // C/D layout: col = lane&15, row = q*4 + reg
#pragma unroll
    for (int mi = 0; mi < 2; mi++) {
#pragma unroll
        for (int ni = 0; ni < 4; ni++) {
            const int rbase = row0 + wy * 32 + mi * 16 + q * 4;
            const int c = col0 + wx * 64 + ni * 16 + n;
#pragma unroll
            for (int r = 0; r < 4; r++) {
                const int rr = rbase + r;
                if (rr >= Mstore) continue;
                float v = acc[mi][ni][r];
                if (Add)  v += bf2f(Add[(size_t)rr * ldadd + c]);
                if (bias) v += bias[c];
                if (relu) v = fmaxf(v, 0.f);
                if (Cf) Cf[(size_t)rr * ldc + c] = v;
                else    Cb[(size_t)rr * ldc + c] = f2bf(v);
            }
        }
    }
}

// ---------- prep: cast z to bf16 (pad rows -> 0) ----------
__global__ __launch_bounds__(256)
void cast_z(const float* __restrict__ z, u16* __restrict__ zb, int N, int Mp)
{
    const int idx = (blockIdx.x * 256 + threadIdx.x) * 4;
    if (idx >= Mp * 128) return;
    const int row = idx >> 7;
    ushort4 u;
    if (row < N) {
        const float4 v = *(const float4*)&z[idx];
        u.x = f2bf(v.x); u.y = f2bf(v.y); u.z = f2bf(v.z); u.w = f2bf(v.w);
    } else {
        u.x = 0; u.y = 0; u.z = 0; u.w = 0;
    }
    *(ushort4*)&zb[idx] = u;
}

// ---------- prep: transpose+cast 5 weight mats to [n][k] bf16 ----------
// Btw rows: 0-127 Wd^T | 128-255 Ws^T | 256-383 W1a^T | 384-511 W1b^T | 512-639 W2^T
__global__ __launch_bounds__(256)
void prep_weights(const float* __restrict__ Wm, const float* __restrict__ W1,
                  const float* __restrict__ W2, u16* __restrict__ Btw)
{
    const int idx = blockIdx.x * 256 + threadIdx.x;
    if (idx >= 640 * 128) return;
    const int nn = idx >> 7, k = idx & 127;
    float v;
    if      (nn < 128) v = Wm[k * 128 + nn];
    else if (nn < 256) v = Wm[(128 + k) * 128 + (nn - 128)];
    else if (nn < 384) v = W1[k * 128 + (nn - 256)];
    else if (nn < 512) v = W1[(128 + k) * 128 + (nn - 384)];
    else               v = W2[k * 128 + (nn - 512)];
    Btw[idx] = f2bf(v);
}

// ---------- counting sort ----------
__global__ __launch_bounds__(256)
void hist_kernel(const int* __restrict__ edst, int* __restrict__ deg, int E)
{
    const int e = blockIdx.x * blockDim.x + threadIdx.x;
    if (e < E) atomicAdd(&deg[edst[e]], 1);
}

__global__ __launch_bounds__(256)
void scan_bsum(const int* __restrict__ deg, int* __restrict__ bsum, int N)
{
    __shared__ int red[4];
    const int t = threadIdx.x;
    const int base = blockIdx.x * 1024 + t * 4;
    int s = 0;
#pragma unroll
    for (int j = 0; j < 4; j++) { int i = base + j; if (i < N) s += deg[i]; }
#pragma unroll
    for (int off = 32; off > 0; off >>= 1) s += __shfl_down(s, off);
    if ((t & 63) == 0) red[t >> 6] = s;
    __syncthreads();
    if (t == 0) bsum[blockIdx.x] = red[0] + red[1] + red[2] + red[3];
}

__global__ void scan_boff(const int* __restrict__ bsum, int* __restrict__ boff, int nb)
{
    if (threadIdx.x == 0) {
        int run = 0;
        for (int i = 0; i < nb; i++) { boff[i] = run; run += bsum[i]; }
    }
}

__global__ __launch_bounds__(256)
void scan_final(const int* __restrict__ deg, const int* __restrict__ boff,
                int* __restrict__ offsets, int* __restrict__ cursor, int N, int E)
{
    __shared__ int ps[256];
    const int t = threadIdx.x;
    const int base = blockIdx.x * 1024 + t * 4;
    int d[4]; int s = 0;
#pragma unroll
    for (int j = 0; j < 4; j++) { int i = base + j; d[j] = (i < N) ? deg[i] : 0; s += d[j]; }
    ps[t] = s;
    __syncthreads();
    for (int off = 1; off < 256; off <<= 1) {
        int add = (t >= off) ? ps[t - off] : 0;
        __syncthreads();
        ps[t] += add;
        __syncthreads();
    }
    int run = ps[t] - s + boff[blockIdx.x];
#pragma unroll
    for (int j = 0; j < 4; j++) {
        int i = base + j;
        if (i < N) { offsets[i] = run; cursor[i] = run; }
        run += d[j];
    }
    if (blockIdx.x == 0 && t == 0) offsets[N] = E;
}

// scatter (src,w) pairs into dst-sorted order as a single float2 stream
__global__ __launch_bounds__(256)
void scatter_kernel(const int* __restrict__ esrc, const int* __restrict__ edst,
                    const float* __restrict__ ew,
                    int* __restrict__ cursor,
                    float2* __restrict__ s_ew, int E)
{
    const int e = blockIdx.x * blockDim.x + threadIdx.x;
    if (e >= E) return;
    const int d = edst[e];
    const int pos = atomicAdd(&cursor[d], 1);
    s_ew[pos] = make_float2(__int_as_float(esrc[e]), ew[e]);
}

// ---------- per-node segmented max + finalize ----------
// one wave (64 thr) per node; thread owns h0 = 2*lane, 2*lane+1.
// P_b is bf16 Mp x 384: [zWd | zWs | zW1a]; gather reads ushort2 from zWs.
__global__ __launch_bounds__(256)
void aggregate_kernel(const u16* __restrict__ Pb,
                      const float* __restrict__ bm,
                      const float* __restrict__ ww,
                      const int* __restrict__ offsets,
                      const float2* __restrict__ s_ew,
                      u16* __restrict__ aggb, int N, int Mp)
{
    const int t = threadIdx.x;
    const int lane = t & 63;
    const int nd = blockIdx.x * 4 + (t >> 6);
    if (nd >= Mp) return;
    const int h0 = lane * 2;
    if (nd >= N) { *(ushort2*)&aggb[(size_t)nd * HID + h0] = make_ushort2(0, 0); return; }

    const int start = offsets[nd];        // wave-uniform
    const int end   = offsets[nd + 1];
    const float ww0 = ww[h0], ww1 = ww[h0 + 1];
    float m0 = -INFINITY, m1 = -INFINITY;

    int e = start;
    for (; e + 1 < end; e += 2) {
        const float2 p0 = s_ew[e];        // wave-uniform address -> scalarized
        const float2 p1 = s_ew[e + 1];
        const int s0 = __float_as_int(p0.x), s1 = __float_as_int(p1.x);
        const ushort2 z0 = *(const ushort2*)&Pb[(size_t)s0 * 384 + 128 + h0];
        const ushort2 z1 = *(const ushort2*)&Pb[(size_t)s1 * 384 + 128 + h0];
        m0 = fmaxf(m0, fmaf(p0.y, ww0, bf2f(z0.x)));
        m1 = fmaxf(m1, fmaf(p0.y, ww1, bf2f(z0.y)));
        m0 = fmaxf(m0, fmaf(p1.y, ww0, bf2f(z1.x)));
        m1 = fmaxf(m1, fmaf(p1.y, ww1, bf2f(z1.y)));
    }
    if (e < end) {
        const float2 p0 = s_ew[e];
        const int s0 = __float_as_int(p0.x);
        const ushort2 z0 = *(const ushort2*)&Pb[(size_t)s0 * 384 + 128 + h0];
        m0 = fmaxf(m0, fmaf(p0.y, ww0, bf2f(z0.x)));
        m1 = fmaxf(m1, fmaf(p0.y, ww1, bf2f(z0.y)));
    }

    ushort2 outv;
    if (end > start) {
        const ushort2 zd = *(const ushort2*)&Pb[(size_t)nd * 384 + h0];
        outv.x = f2bf(bf2f(zd.x) + bm[h0]     + m0);
        outv.y = f2bf(bf2f(zd.y) + bm[h0 + 1] + m1);
    } else {
        outv.x = 0; outv.y = 0;
    }
    *(ushort2*)&aggb[(size_t)nd * HID + h0] = outv;
}

extern "C" void kernel_launch(void* const* d_in, const int* in_sizes, int n_in,
                              void* d_out, int out_size, void* d_ws, size_t ws_size,
                              hipStream_t stream) {
    const float* z    = (const float*)d_in[0];
    const float* ew   = (const float*)d_in[1];
    const int*   esrc = (const int*)d_in[2];
    const int*   edst = (const int*)d_in[3];
    const float* Wm   = (const float*)d_in[4];
    const float* bm   = (const float*)d_in[5];
    const float* W1   = (const float*)d_in[6];
    const float* b1   = (const float*)d_in[7];
    const float* W2   = (const float*)d_in[8];
    const float* b2   = (const float*)d_in[9];
    float* out = (float*)d_out;

    const int N  = in_sizes[0] / HID;          // 50000
    const int E  = in_sizes[1];                // 800000
    const int Mp = ((N + 63) / 64) * 64;       // padded rows (50048)

    // workspace layout
    char* w = (char*)d_ws;
    u16*  Pb       = (u16*)w;    w += (size_t)Mp * 384 * 2;   // bf16 [zWd|zWs|zW1a]
    u16*  zb       = (u16*)w;    w += (size_t)Mp * 128 * 2;
    u16*  aggb     = (u16*)w;    w += (size_t)Mp * 128 * 2;
    u16*  hiddenb  = (u16*)w;    w += (size_t)Mp * 128 * 2;
    u16*  Btw      = (u16*)w;    w += (size_t)640 * 128 * 2;
    int*  deg      = (int*)w;    w += (size_t)(N + 64) * 4;
    int*  offsets  = (int*)w;    w += (size_t)(N + 64) * 4;
    int*  cursor   = (int*)w;    w += (size_t)(N + 64) * 4;
    int*  bsum     = (int*)w;    w += 256;
    int*  boff     = (int*)w;    w += 256;
    float2* s_ew   = (float2*)w; w += (size_t)E * 8;

    const int nb = (N + 1023) / 1024;          // scan blocks

    // --- counting sort of edges by dst ---
    hipMemsetAsync(deg, 0, (size_t)N * sizeof(int), stream);
    hist_kernel<<<(E + 255) / 256, 256, 0, stream>>>(edst, deg, E);
    scan_bsum<<<nb, 256, 0, stream>>>(deg, bsum, N);
    scan_boff<<<1, 64, 0, stream>>>(bsum, boff, nb);
    scan_final<<<nb, 256, 0, stream>>>(deg, boff, offsets, cursor, N, E);
    scatter_kernel<<<(E + 255) / 256, 256, 0, stream>>>(esrc, edst, ew, cursor, s_ew, E);

    // --- bf16 prep ---
    cast_z<<<(Mp * 128 / 4 + 255) / 256, 256, 0, stream>>>(z, zb, N, Mp);
    prep_weights<<<(640 * 128 + 255) / 256, 256, 0, stream>>>(Wm, W1, W2, Btw);

    // --- Pb = z @ [Wd | Ws | W1a]  (bf16 out) ---
    gemm_mfma<<<dim3(Mp / 64, 3), 256, 0, stream>>>(zb, Btw, nullptr, 0, nullptr,
                                                    nullptr, Pb, 384, Mp, 0);

    // --- segmented max + finalize -> aggb (bf16) ---
    aggregate_kernel<<<Mp / 4, 256, 0, stream>>>(Pb, bm, Wm + 256 * 128,
                                                 offsets, s_ew, aggb, N, Mp);

    // --- hidden = relu(agg @ W1b + zW1a + b1) -> bf16 ---
    gemm_mfma<<<dim3(Mp / 64, 1), 256, 0, stream>>>(aggb, Btw + 384 * 128, Pb + 256, 384,
                                                    b1, nullptr, hiddenb, 128, Mp, 1);

    // --- out = hidden @ W2 + b2 (fp32) ---
    gemm_mfma<<<dim3(Mp / 64, 1), 256, 0, stream>>>(hiddenb, Btw + 512 * 128, nullptr, 0,
                                                    b2, out, nullptr, 128, N, 0);
}

// Round 5
// 312.685 us; speedup vs baseline: 2.1157x; 1.0359x over previous
//
#include <hip/hip_runtime.h>
#include <hip/hip_bf16.h>

#define HID 128

typedef short bf16x8 __attribute__((ext_vector_type(8)));
typedef float f32x4  __attribute__((ext_vector_type(4)));
typedef unsigned short u16;

__device__ __forceinline__ u16 f2bf(float f) {
    __hip_bfloat16 h = __float2bfloat16(f);
    return *reinterpret_cast<u16*>(&h);
}
__device__ __forceinline__ float bf2f(u16 x) {
    unsigned u = ((unsigned)x) << 16;
    return __uint_as_float(u);
}

// Wt layout (u16): [0,32768) Wds^T (256 rows x 128k: Wd^T then Ws^T)
//                  [32768,65536) W1^T (128 rows x 256k)
//                  [65536,81920) W2^T (128 rows x 128k)

// ---------- fused prep (z-cast + weight transpose/cast) + edge histogram ----------
__global__ __launch_bounds__(256)
void prep_hist(const float* __restrict__ z, const float* __restrict__ Wm,
               const float* __restrict__ W1, const float* __restrict__ W2,
               const int* __restrict__ edst,
               u16* __restrict__ Ab, u16* __restrict__ Wt, int* __restrict__ deg,
               int N, int Mp, int E, int bz, int bw)
{
    const int b = blockIdx.x;
    const int t = threadIdx.x;
    if (b < bz) {
        const int idx4 = (b * 256 + t) * 4;
        if (idx4 >= Mp * 128) return;
        const int row = idx4 >> 7, col = idx4 & 127;
        ushort4 u;
        if (row < N) {
            const float4 v = *(const float4*)&z[(size_t)row * 128 + col];
            u.x = f2bf(v.x); u.y = f2bf(v.y); u.z = f2bf(v.z); u.w = f2bf(v.w);
        } else { u.x = 0; u.y = 0; u.z = 0; u.w = 0; }
        *(ushort4*)&Ab[(size_t)row * 256 + col] = u;
    } else if (b < bz + bw) {
        const int idx = (b - bz) * 256 + t;
        if (idx >= 81920) return;
        float v;
        if (idx < 32768) {
            const int nn = idx >> 7, k = idx & 127;
            v = (nn < 128) ? Wm[k * 128 + nn] : Wm[(128 + k) * 128 + (nn - 128)];
        } else if (idx < 65536) {
            const int j = idx - 32768, n = j >> 8, k = j & 255;
            v = W1[k * 128 + n];
        } else {
            const int j = idx - 65536, n = j >> 7, k = j & 127;
            v = W2[k * 128 + n];
        }
        Wt[idx] = f2bf(v);
    } else {
        const int e = (b - bz - bw) * 256 + t;
        if (e < E) atomicAdd(&deg[edst[e]], 1);
    }
}

// ---------- single-kernel exclusive scan (each block redundantly sums its prefix) ----------
__global__ __launch_bounds__(256)
void scan_all(const int* __restrict__ deg, int* __restrict__ offsets,
              int* __restrict__ cursor, int N, int E)
{
    __shared__ int ps[256];
    __shared__ int red[4];
    const int t = threadIdx.x;
    const int base0 = blockIdx.x * 1024;

    // prefix sum of all deg before this block (<=48k values, cooperative)
    int pre = 0;
    for (int i = t; i < base0; i += 256) pre += deg[i];
    int s = pre;
#pragma unroll
    for (int off = 32; off > 0; off >>= 1) s += __shfl_down(s, off);
    if ((t & 63) == 0) red[t >> 6] = s;
    __syncthreads();
    const int block_pre = red[0] + red[1] + red[2] + red[3];

    // local scan of this block's 1024 degrees
    const int base = base0 + t * 4;
    int d[4]; int ls = 0;
#pragma unroll
    for (int j = 0; j < 4; j++) { int i = base + j; d[j] = (i < N) ? deg[i] : 0; ls += d[j]; }
    __syncthreads();
    ps[t] = ls;
    __syncthreads();
    for (int off = 1; off < 256; off <<= 1) {
        int add = (t >= off) ? ps[t - off] : 0;
        __syncthreads();
        ps[t] += add;
        __syncthreads();
    }
    int run = ps[t] - ls + block_pre;
#pragma unroll
    for (int j = 0; j < 4; j++) {
        int i = base + j;
        if (i < N) { offsets[i] = run; cursor[i] = run; }
        run += d[j];
    }
    if (blockIdx.x == 0 && t == 0) offsets[N] = E;
}

// ---------- scatter (src,w) into dst-sorted float2 stream ----------
__global__ __launch_bounds__(256)
void scatter_kernel(const int* __restrict__ esrc, const int* __restrict__ edst,
                    const float* __restrict__ ew, int* __restrict__ cursor,
                    float2* __restrict__ s_ew, int E)
{
    const int e = blockIdx.x * blockDim.x + threadIdx.x;
    if (e >= E) return;
    const int d = edst[e];
    const int pos = atomicAdd(&cursor[d], 1);
    s_ew[pos] = make_float2(__int_as_float(esrc[e]), ew[e]);
}

// ---------- Pb = z @ [Wd | Ws]  (64 rows x 256 cols per block, K=128) ----------
__global__ __launch_bounds__(256)
void gemm_P(const u16* __restrict__ Ab, const u16* __restrict__ Wds_t,
            u16* __restrict__ Pb, int Mp)
{
    const int row0 = blockIdx.x * 64;
    const int tid = threadIdx.x;
    const int wv = tid >> 6, lane = tid & 63;
    const int wy = wv & 1, wx = wv >> 1;   // wy: row half, wx: 128-col half
    const int q = lane >> 4, n = lane & 15;

    const u16* pA = Ab + (size_t)(row0 + wy * 32 + n) * 256 + q * 8;
    const u16* pB = Wds_t + (size_t)(wx * 128 + n) * 128 + q * 8;

    f32x4 acc[2][8];
#pragma unroll
    for (int i = 0; i < 2; i++)
#pragma unroll
        for (int j = 0; j < 8; j++) acc[i][j] = f32x4{0.f, 0.f, 0.f, 0.f};

#pragma unroll
    for (int kk = 0; kk < 128; kk += 32) {
        bf16x8 a0 = *(const bf16x8*)(pA + kk);
        bf16x8 a1 = *(const bf16x8*)(pA + 16 * 256 + kk);
        bf16x8 bfr[8];
#pragma unroll
        for (int ni = 0; ni < 8; ni++)
            bfr[ni] = *(const bf16x8*)(pB + (size_t)ni * 16 * 128 + kk);
#pragma unroll
        for (int ni = 0; ni < 8; ni++) {
            acc[0][ni] = __builtin_amdgcn_mfma_f32_16x16x32_bf16(a0, bfr[ni], acc[0][ni], 0, 0, 0);
            acc[1][ni] = __builtin_amdgcn_mfma_f32_16x16x32_bf16(a1, bfr[ni], acc[1][ni], 0, 0, 0);
        }
    }

#pragma unroll
    for (int mi = 0; mi < 2; mi++) {
#pragma unroll
        for (int ni = 0; ni < 8; ni++) {
            const int rbase = row0 + wy * 32 + mi * 16 + q * 4;
            const int c = wx * 128 + ni * 16 + n;
#pragma unroll
            for (int r = 0; r < 4; r++)
                Pb[(size_t)(rbase + r) * 256 + c] = f2bf(acc[mi][ni][r]);
        }
    }
}

// ---------- per-node segmented max + finalize -> Ab agg slice ----------
// one wave per node; lane owns h0 = 2*lane, 2*lane+1; unroll 4 for MLP.
__global__ __launch_bounds__(256)
void aggregate_kernel(const u16* __restrict__ Pb,
                      const float* __restrict__ bm,
                      const float* __restrict__ ww,
                      const int* __restrict__ offsets,
                      const float2* __restrict__ s_ew,
                      u16* __restrict__ Ab, int N, int Mp)
{
    const int t = threadIdx.x;
    const int lane = t & 63;
    const int nd = blockIdx.x * 4 + (t >> 6);
    if (nd >= Mp) return;
    const int h0 = lane * 2;
    u16* dst = &Ab[(size_t)nd * 256 + 128 + h0];
    if (nd >= N) { *(ushort2*)dst = make_ushort2(0, 0); return; }

    const int start = offsets[nd];       // wave-uniform
    const int end   = offsets[nd + 1];
    const float ww0 = ww[h0], ww1 = ww[h0 + 1];
    float m0 = -INFINITY, m1 = -INFINITY;

    int e = start;
    for (; e + 3 < end; e += 4) {
        const float2 p0 = s_ew[e];
        const float2 p1 = s_ew[e + 1];
        const float2 p2 = s_ew[e + 2];
        const float2 p3 = s_ew[e + 3];
        const ushort2 z0 = *(const ushort2*)&Pb[(size_t)__float_as_int(p0.x) * 256 + 128 + h0];
        const ushort2 z1 = *(const ushort2*)&Pb[(size_t)__float_as_int(p1.x) * 256 + 128 + h0];
        const ushort2 z2 = *(const ushort2*)&Pb[(size_t)__float_as_int(p2.x) * 256 + 128 + h0];
        const ushort2 z3 = *(const ushort2*)&Pb[(size_t)__float_as_int(p3.x) * 256 + 128 + h0];
        const float a0 = fmaf(p0.y, ww0, bf2f(z0.x)), b0 = fmaf(p0.y, ww1, bf2f(z0.y));
        const float a1 = fmaf(p1.y, ww0, bf2f(z1.x)), b1v = fmaf(p1.y, ww1, bf2f(z1.y));
        const float a2 = fmaf(p2.y, ww0, bf2f(z2.x)), b2v = fmaf(p2.y, ww1, bf2f(z2.y));
        const float a3 = fmaf(p3.y, ww0, bf2f(z3.x)), b3v = fmaf(p3.y, ww1, bf2f(z3.y));
        m0 = fmaxf(m0, fmaxf(fmaxf(a0, a1), fmaxf(a2, a3)));
        m1 = fmaxf(m1, fmaxf(fmaxf(b0, b1v), fmaxf(b2v, b3v)));
    }
    for (; e < end; e++) {
        const float2 p0 = s_ew[e];
        const ushort2 z0 = *(const ushort2*)&Pb[(size_t)__float_as_int(p0.x) * 256 + 128 + h0];
        m0 = fmaxf(m0, fmaf(p0.y, ww0, bf2f(z0.x)));
        m1 = fmaxf(m1, fmaf(p0.y, ww1, bf2f(z0.y)));
    }

    ushort2 outv;
    if (end > start) {
        const ushort2 zd = *(const ushort2*)&Pb[(size_t)nd * 256 + h0];
        outv.x = f2bf(bf2f(zd.x) + bm[h0]     + m0);
        outv.y = f2bf(bf2f(zd.y) + bm[h0 + 1] + m1);
    } else { outv.x = 0; outv.y = 0; }
    *(ushort2*)dst = outv;
}

// ---------- hidden = relu([z|agg] @ W1 + b1), K=256 -> bf16 ----------
__global__ __launch_bounds__(256)
void gemm_H(const u16* __restrict__ Ab, const u16* __restrict__ W1t,
            const float* __restrict__ b1, u16* __restrict__ Hb, int Mp)
{
    const int row0 = blockIdx.x * 64;
    const int tid = threadIdx.x;
    const int wv = tid >> 6, lane = tid & 63;
    const int wy = wv & 1, wx = wv >> 1;
    const int q = lane >> 4, n = lane & 15;

    const u16* pA = Ab + (size_t)(row0 + wy * 32 + n) * 256 + q * 8;
    const u16* pB = W1t + (size_t)(wx * 64 + n) * 256 + q * 8;

    f32x4 acc[2][4];
#pragma unroll
    for (int i = 0; i < 2; i++)
#pragma unroll
        for (int j = 0; j < 4; j++) acc[i][j] = f32x4{0.f, 0.f, 0.f, 0.f};

#pragma unroll
    for (int kk = 0; kk < 256; kk += 32) {
        bf16x8 a0 = *(const bf16x8*)(pA + kk);
        bf16x8 a1 = *(const bf16x8*)(pA + 16 * 256 + kk);
        bf16x8 b0 = *(const bf16x8*)(pB + kk);
        bf16x8 b1f = *(const bf16x8*)(pB + 16 * 256 + kk);
        bf16x8 b2f = *(const bf16x8*)(pB + 32 * 256 + kk);
        bf16x8 b3f = *(const bf16x8*)(pB + 48 * 256 + kk);
        acc[0][0] = __builtin_amdgcn_mfma_f32_16x16x32_bf16(a0, b0,  acc[0][0], 0, 0, 0);
        acc[0][1] = __builtin_amdgcn_mfma_f32_16x16x32_bf16(a0, b1f, acc[0][1], 0, 0, 0);
        acc[0][2] = __builtin_amdgcn_mfma_f32_16x16x32_bf16(a0, b2f, acc[0][2], 0, 0, 0);
        acc[0][3] = __builtin_amdgcn_mfma_f32_16x16x32_bf16(a0, b3f, acc[0][3], 0, 0, 0);
        acc[1][0] = __builtin_amdgcn_mfma_f32_16x16x32_bf16(a1, b0,  acc[1][0], 0, 0, 0);
        acc[1][1] = __builtin_amdgcn_mfma_f32_16x16x32_bf16(a1, b1f, acc[1][1], 0, 0, 0);
        acc[1][2] = __builtin_amdgcn_mfma_f32_16x16x32_bf16(a1, b2f, acc[1][2], 0, 0, 0);
        acc[1][3] = __builtin_amdgcn_mfma_f32_16x16x32_bf16(a1, b3f, acc[1][3], 0, 0, 0);
    }

#pragma unroll
    for (int mi = 0; mi < 2; mi++) {
#pragma unroll
        for (int ni = 0; ni < 4; ni++) {
            const int rbase = row0 + wy * 32 + mi * 16 + q * 4;
            const int c = wx * 64 + ni * 16 + n;
#pragma unroll
            for (int r = 0; r < 4; r++) {
                float v = acc[mi][ni][r] + b1[c];
                Hb[(size_t)(rbase + r) * 128 + c] = f2bf(fmaxf(v, 0.f));
            }
        }
    }
}

// ---------- out = hidden @ W2 + b2 -> fp32 ----------
__global__ __launch_bounds__(256)
void gemm_O(const u16* __restrict__ Hb, const u16* __restrict__ W2t,
            const float* __restrict__ b2, float* __restrict__ out, int Mstore)
{
    const int row0 = blockIdx.x * 64;
    const int tid = threadIdx.x;
    const int wv = tid >> 6, lane = tid & 63;
    const int wy = wv & 1, wx = wv >> 1;
    const int q = lane >> 4, n = lane & 15;

    const u16* pA = Hb + (size_t)(row0 + wy * 32 + n) * 128 + q * 8;
    const u16* pB = W2t + (size_t)(wx * 64 + n) * 128 + q * 8;

    f32x4 acc[2][4];
#pragma unroll
    for (int i = 0; i < 2; i++)
#pragma unroll
        for (int j = 0; j < 4; j++) acc[i][j] = f32x4{0.f, 0.f, 0.f, 0.f};

#pragma unroll
    for (int kk = 0; kk < 128; kk += 32) {
        bf16x8 a0 = *(const bf16x8*)(pA + kk);
        bf16x8 a1 = *(const bf16x8*)(pA + 16 * 128 + kk);
        bf16x8 b0 = *(const bf16x8*)(pB + kk);
        bf16x8 b1f = *(const bf16x8*)(pB + 16 * 128 + kk);
        bf16x8 b2f = *(const bf16x8*)(pB + 32 * 128 + kk);
        bf16x8 b3f = *(const bf16x8*)(pB + 48 * 128 + kk);
        acc[0][0] = __builtin_amdgcn_mfma_f32_16x16x32_bf16(a0, b0,  acc[0][0], 0, 0, 0);
        acc[0][1] = __builtin_amdgcn_mfma_f32_16x16x32_bf16(a0, b1f, acc[0][1], 0, 0, 0);
        acc[0][2] = __builtin_amdgcn_mfma_f32_16x16x32_bf16(a0, b2f, acc[0][2], 0, 0, 0);
        acc[0][3] = __builtin_amdgcn_mfma_f32_16x16x32_bf16(a0, b3f, acc[0][3], 0, 0, 0);
        acc[1][0] = __builtin_amdgcn_mfma_f32_16x16x32_bf16(a1, b0,  acc[1][0], 0, 0, 0);
        acc[1][1] = __builtin_amdgcn_mfma_f32_16x16x32_bf16(a1, b1f, acc[1][1], 0, 0, 0);
        acc[1][2] = __builtin_amdgcn_mfma_f32_16x16x32_bf16(a1, b2f, acc[1][2], 0, 0, 0);
        acc[1][3] = __builtin_amdgcn_mfma_f32_16x16x32_bf16(a1, b3f, acc[1][3], 0, 0, 0);
    }

#pragma unroll
    for (int mi = 0; mi < 2; mi++) {
#pragma unroll
        for (int ni = 0; ni < 4; ni++) {
            const int rbase = row0 + wy * 32 + mi * 16 + q * 4;
            const int c = wx * 64 + ni * 16 + n;
#pragma unroll
            for (int r = 0; r < 4; r++) {
                const int rr = rbase + r;
                if (rr >= Mstore) continue;
                out[(size_t)rr * 128 + c] = acc[mi][ni][r] + b2[c];
            }
        }
    }
}

extern "C" void kernel_launch(void* const* d_in, const int* in_sizes, int n_in,
                              void* d_out, int out_size, void* d_ws, size_t ws_size,
                              hipStream_t stream) {
    const float* z    = (const float*)d_in[0];
    const float* ew   = (const float*)d_in[1];
    const int*   esrc = (const int*)d_in[2];
    const int*   edst = (const int*)d_in[3];
    const float* Wm   = (const float*)d_in[4];
    const float* bm   = (const float*)d_in[5];
    const float* W1   = (const float*)d_in[6];
    const float* b1   = (const float*)d_in[7];
    const float* W2   = (const float*)d_in[8];
    const float* b2   = (const float*)d_in[9];
    float* out = (float*)d_out;

    const int N  = in_sizes[0] / HID;          // 50000
    const int E  = in_sizes[1];                // 800000
    const int Mp = ((N + 63) / 64) * 64;       // 50048

    // workspace layout
    char* w = (char*)d_ws;
    u16*  Ab      = (u16*)w;    w += (size_t)Mp * 256 * 2;   // [zb | aggb]
    u16*  Pb      = (u16*)w;    w += (size_t)Mp * 256 * 2;   // [zWd | zWs]
    u16*  Hb      = (u16*)w;    w += (size_t)Mp * 128 * 2;
    u16*  Wt      = (u16*)w;    w += (size_t)81920 * 2;
    int*  deg     = (int*)w;    w += (size_t)(N + 64) * 4;
    int*  offsets = (int*)w;    w += (size_t)(N + 64) * 4;
    int*  cursor  = (int*)w;    w += (size_t)(N + 64) * 4;
    float2* s_ew  = (float2*)w; w += (size_t)E * 8;

    const int bz = (Mp * 32 + 255) / 256;      // z-cast blocks
    const int bw = (81920 + 255) / 256;        // weight blocks
    const int bh = (E + 255) / 256;            // hist blocks

    hipMemsetAsync(deg, 0, (size_t)N * sizeof(int), stream);
    prep_hist<<<bz + bw + bh, 256, 0, stream>>>(z, Wm, W1, W2, edst, Ab, Wt, deg,
                                                N, Mp, E, bz, bw);
    scan_all<<<(N + 1023) / 1024, 256, 0, stream>>>(deg, offsets, cursor, N, E);
    scatter_kernel<<<(E + 255) / 256, 256, 0, stream>>>(esrc, edst, ew, cursor, s_ew, E);

    gemm_P<<<Mp / 64, 256, 0, stream>>>(Ab, Wt, Pb, Mp);
    aggregate_kernel<<<(Mp + 3) / 4, 256, 0, stream>>>(Pb, bm, Wm + 256 * 128,
                                                       offsets, s_ew, Ab, N, Mp);
    gemm_H<<<Mp / 64, 256, 0, stream>>>(Ab, Wt + 32768, b1, Hb, Mp);
    gemm_O<<<Mp / 64, 256, 0, stream>>>(Hb, Wt + 65536, b2, out, N);
}

// Round 6
// 310.705 us; speedup vs baseline: 2.1292x; 1.0064x over previous
//
#include <hip/hip_runtime.h>
#include <hip/hip_bf16.h>

#define HID 128

typedef short bf16x8 __attribute__((ext_vector_type(8)));
typedef float f32x4  __attribute__((ext_vector_type(4)));
typedef unsigned short u16;

__device__ __forceinline__ u16 f2bf(float f) {
    __hip_bfloat16 h = __float2bfloat16(f);
    return *reinterpret_cast<u16*>(&h);
}
__device__ __forceinline__ float bf2f(u16 x) {
    unsigned u = ((unsigned)x) << 16;
    return __uint_as_float(u);
}
__device__ __forceinline__ unsigned pack_ew(int src, float w) {
    int wq = (int)fmaf(w, 32768.f, 0.5f);
    wq = wq > 32767 ? 32767 : wq;
    return ((unsigned)src << 15) | (unsigned)wq;
}

// Wt layout (u16): [0,32768) Wds^T (256 rows x 128k: Wd^T then Ws^T)
//                  [32768,65536) W1^T (128 rows x 256k)
//                  [65536,81920) W2^T (128 rows x 128k)

// ---------- fused prep (z-cast + weight transpose/cast) + edge histogram ----------
__global__ __launch_bounds__(256)
void prep_hist(const float* __restrict__ z, const float* __restrict__ Wm,
               const float* __restrict__ W1, const float* __restrict__ W2,
               const int* __restrict__ edst,
               u16* __restrict__ Ab, u16* __restrict__ Wt, int* __restrict__ deg,
               int N, int Mp, int E, int bz, int bw)
{
    const int b = blockIdx.x;
    const int t = threadIdx.x;
    if (b < bz) {
        const int idx4 = (b * 256 + t) * 4;
        if (idx4 >= Mp * 128) return;
        const int row = idx4 >> 7, col = idx4 & 127;
        ushort4 u;
        if (row < N) {
            const float4 v = *(const float4*)&z[(size_t)row * 128 + col];
            u.x = f2bf(v.x); u.y = f2bf(v.y); u.z = f2bf(v.z); u.w = f2bf(v.w);
        } else { u.x = 0; u.y = 0; u.z = 0; u.w = 0; }
        *(ushort4*)&Ab[(size_t)row * 256 + col] = u;
    } else if (b < bz + bw) {
        const int idx = (b - bz) * 256 + t;
        if (idx >= 81920) return;
        float v;
        if (idx < 32768) {
            const int nn = idx >> 7, k = idx & 127;
            v = (nn < 128) ? Wm[k * 128 + nn] : Wm[(128 + k) * 128 + (nn - 128)];
        } else if (idx < 65536) {
            const int j = idx - 32768, n = j >> 8, k = j & 255;
            v = W1[k * 128 + n];
        } else {
            const int j = idx - 65536, n = j >> 7, k = j & 127;
            v = W2[k * 128 + n];
        }
        Wt[idx] = f2bf(v);
    } else {
        const int e = (b - bz - bw) * 256 + t;
        if (e < E) atomicAdd(&deg[edst[e]], 1);
    }
}

// ---------- single-kernel exclusive scan (blocks redundantly sum their prefix) ----------
__global__ __launch_bounds__(256)
void scan_all(const int* __restrict__ deg, int* __restrict__ offsets,
              int* __restrict__ cursor, int N, int E)
{
    __shared__ int ps[256];
    __shared__ int red[4];
    const int t = threadIdx.x;
    const int base0 = blockIdx.x * 1024;

    int pre = 0;
    for (int i = t; i < base0; i += 256) pre += deg[i];
    int s = pre;
#pragma unroll
    for (int off = 32; off > 0; off >>= 1) s += __shfl_down(s, off);
    if ((t & 63) == 0) red[t >> 6] = s;
    __syncthreads();
    const int block_pre = red[0] + red[1] + red[2] + red[3];

    const int base = base0 + t * 4;
    int d[4]; int ls = 0;
#pragma unroll
    for (int j = 0; j < 4; j++) { int i = base + j; d[j] = (i < N) ? deg[i] : 0; ls += d[j]; }
    __syncthreads();
    ps[t] = ls;
    __syncthreads();
    for (int off = 1; off < 256; off <<= 1) {
        int add = (t >= off) ? ps[t - off] : 0;
        __syncthreads();
        ps[t] += add;
        __syncthreads();
    }
    int run = ps[t] - ls + block_pre;
#pragma unroll
    for (int j = 0; j < 4; j++) {
        int i = base + j;
        if (i < N) { offsets[i] = run; cursor[i] = run; }
        run += d[j];
    }
    if (blockIdx.x == 0 && t == 0) offsets[N] = E;
}

// ---------- scatter packed 4B records into dst-sorted stream, 4 edges/thread ----------
__global__ __launch_bounds__(256)
void scatter_kernel(const int* __restrict__ esrc, const int* __restrict__ edst,
                    const float* __restrict__ ew, int* __restrict__ cursor,
                    unsigned* __restrict__ s_ew, int E)
{
    const int e0 = (blockIdx.x * 256 + threadIdx.x) * 4;
    if (e0 + 3 < E) {
        const int4   s4 = *(const int4*)&esrc[e0];
        const int4   d4 = *(const int4*)&edst[e0];
        const float4 w4 = *(const float4*)&ew[e0];
        const int p0 = atomicAdd(&cursor[d4.x], 1);
        const int p1 = atomicAdd(&cursor[d4.y], 1);
        const int p2 = atomicAdd(&cursor[d4.z], 1);
        const int p3 = atomicAdd(&cursor[d4.w], 1);
        s_ew[p0] = pack_ew(s4.x, w4.x);
        s_ew[p1] = pack_ew(s4.y, w4.y);
        s_ew[p2] = pack_ew(s4.z, w4.z);
        s_ew[p3] = pack_ew(s4.w, w4.w);
    } else {
        for (int e = e0; e < E; e++) {
            const int pos = atomicAdd(&cursor[edst[e]], 1);
            s_ew[pos] = pack_ew(esrc[e], ew[e]);
        }
    }
}

// ---------- Pb = z @ [Wd | Ws]  (64 rows x 256 cols per block, K=128) ----------
__global__ __launch_bounds__(256)
void gemm_P(const u16* __restrict__ Ab, const u16* __restrict__ Wds_t,
            u16* __restrict__ Pb, int Mp)
{
    const int row0 = blockIdx.x * 64;
    const int tid = threadIdx.x;
    const int wv = tid >> 6, lane = tid & 63;
    const int wy = wv & 1, wx = wv >> 1;
    const int q = lane >> 4, n = lane & 15;

    const u16* pA = Ab + (size_t)(row0 + wy * 32 + n) * 256 + q * 8;
    const u16* pB = Wds_t + (size_t)(wx * 128 + n) * 128 + q * 8;

    f32x4 acc[2][8];
#pragma unroll
    for (int i = 0; i < 2; i++)
#pragma unroll
        for (int j = 0; j < 8; j++) acc[i][j] = f32x4{0.f, 0.f, 0.f, 0.f};

#pragma unroll
    for (int kk = 0; kk < 128; kk += 32) {
        bf16x8 a0 = *(const bf16x8*)(pA + kk);
        bf16x8 a1 = *(const bf16x8*)(pA + 16 * 256 + kk);
        bf16x8 bfr[8];
#pragma unroll
        for (int ni = 0; ni < 8; ni++)
            bfr[ni] = *(const bf16x8*)(pB + (size_t)ni * 16 * 128 + kk);
#pragma unroll
        for (int ni = 0; ni < 8; ni++) {
            acc[0][ni] = __builtin_amdgcn_mfma_f32_16x16x32_bf16(a0, bfr[ni], acc[0][ni], 0, 0, 0);
            acc[1][ni] = __builtin_amdgcn_mfma_f32_16x16x32_bf16(a1, bfr[ni], acc[1][ni], 0, 0, 0);
        }
    }

#pragma unroll
    for (int mi = 0; mi < 2; mi++) {
#pragma unroll
        for (int ni = 0; ni < 8; ni++) {
            const int rbase = row0 + wy * 32 + mi * 16 + q * 4;
            const int c = wx * 128 + ni * 16 + n;
#pragma unroll
            for (int r = 0; r < 4; r++)
                Pb[(size_t)(rbase + r) * 256 + c] = f2bf(acc[mi][ni][r]);
        }
    }
}

// ---------- per-node segmented max + finalize -> Ab agg slice ----------
__global__ __launch_bounds__(256)
void aggregate_kernel(const u16* __restrict__ Pb,
                      const float* __restrict__ bm,
                      const float* __restrict__ ww,
                      const int* __restrict__ offsets,
                      const unsigned* __restrict__ s_ew,
                      u16* __restrict__ Ab, int N, int Mp)
{
    const int t = threadIdx.x;
    const int lane = t & 63;
    const int nd = blockIdx.x * 4 + (t >> 6);
    if (nd >= Mp) return;
    const int h0 = lane * 2;
    u16* dst = &Ab[(size_t)nd * 256 + 128 + h0];
    if (nd >= N) { *(ushort2*)dst = make_ushort2(0, 0); return; }

    const int start = offsets[nd];       // wave-uniform
    const int end   = offsets[nd + 1];
    const float ww0 = ww[h0], ww1 = ww[h0 + 1];
    const float kq = 1.f / 32768.f;
    float m0 = -INFINITY, m1 = -INFINITY;

    int e = start;
    for (; e + 3 < end; e += 4) {
        const unsigned u0 = s_ew[e],     u1 = s_ew[e + 1];
        const unsigned u2 = s_ew[e + 2], u3 = s_ew[e + 3];
        const float w0 = (float)(u0 & 32767u) * kq;
        const float w1 = (float)(u1 & 32767u) * kq;
        const float w2 = (float)(u2 & 32767u) * kq;
        const float w3 = (float)(u3 & 32767u) * kq;
        const ushort2 z0 = *(const ushort2*)&Pb[(size_t)(u0 >> 15) * 256 + 128 + h0];
        const ushort2 z1 = *(const ushort2*)&Pb[(size_t)(u1 >> 15) * 256 + 128 + h0];
        const ushort2 z2 = *(const ushort2*)&Pb[(size_t)(u2 >> 15) * 256 + 128 + h0];
        const ushort2 z3 = *(const ushort2*)&Pb[(size_t)(u3 >> 15) * 256 + 128 + h0];
        const float a0 = fmaf(w0, ww0, bf2f(z0.x)), c0 = fmaf(w0, ww1, bf2f(z0.y));
        const float a1 = fmaf(w1, ww0, bf2f(z1.x)), c1 = fmaf(w1, ww1, bf2f(z1.y));
        const float a2 = fmaf(w2, ww0, bf2f(z2.x)), c2 = fmaf(w2, ww1, bf2f(z2.y));
        const float a3 = fmaf(w3, ww0, bf2f(z3.x)), c3 = fmaf(w3, ww1, bf2f(z3.y));
        m0 = fmaxf(m0, fmaxf(fmaxf(a0, a1), fmaxf(a2, a3)));
        m1 = fmaxf(m1, fmaxf(fmaxf(c0, c1), fmaxf(c2, c3)));
    }
    for (; e < end; e++) {
        const unsigned u0 = s_ew[e];
        const float w0 = (float)(u0 & 32767u) * kq;
        const ushort2 z0 = *(const ushort2*)&Pb[(size_t)(u0 >> 15) * 256 + 128 + h0];
        m0 = fmaxf(m0, fmaf(w0, ww0, bf2f(z0.x)));
        m1 = fmaxf(m1, fmaf(w0, ww1, bf2f(z0.y)));
    }

    ushort2 outv;
    if (end > start) {
        const ushort2 zd = *(const ushort2*)&Pb[(size_t)nd * 256 + h0];
        outv.x = f2bf(bf2f(zd.x) + bm[h0]     + m0);
        outv.y = f2bf(bf2f(zd.y) + bm[h0 + 1] + m1);
    } else { outv.x = 0; outv.y = 0; }
    *(ushort2*)dst = outv;
}

// ---------- fused: H = relu([z|agg]@W1+b1) (K=256) -> LDS -> out = H@W2+b2 ----------
__global__ __launch_bounds__(256)
void gemm_HO(const u16* __restrict__ Ab, const u16* __restrict__ W1t,
             const float* __restrict__ b1, const u16* __restrict__ W2t,
             const float* __restrict__ b2, float* __restrict__ out, int Mstore)
{
    __shared__ u16 Hs[64][136];   // 136-short pitch: 16B-aligned rows, 2-way banks (free)

    const int row0 = blockIdx.x * 64;
    const int tid = threadIdx.x;
    const int wv = tid >> 6, lane = tid & 63;
    const int wy = wv & 1, wx = wv >> 1;
    const int q = lane >> 4, n = lane & 15;

    // ---- phase 1: H tile (64 x 128), K=256 ----
    {
        const u16* pA = Ab + (size_t)(row0 + wy * 32 + n) * 256 + q * 8;
        const u16* pB = W1t + (size_t)(wx * 64 + n) * 256 + q * 8;

        f32x4 acc[2][4];
#pragma unroll
        for (int i = 0; i < 2; i++)
#pragma unroll
            for (int j = 0; j < 4; j++) acc[i][j] = f32x4{0.f, 0.f, 0.f, 0.f};

#pragma unroll
        for (int kk = 0; kk < 256; kk += 32) {
            bf16x8 a0 = *(const bf16x8*)(pA + kk);
            bf16x8 a1 = *(const bf16x8*)(pA + 16 * 256 + kk);
            bf16x8 b0 = *(const bf16x8*)(pB + kk);
            bf16x8 b1f = *(const bf16x8*)(pB + 16 * 256 + kk);
            bf16x8 b2f = *(const bf16x8*)(pB + 32 * 256 + kk);
            bf16x8 b3f = *(const bf16x8*)(pB + 48 * 256 + kk);
            acc[0][0] = __builtin_amdgcn_mfma_f32_16x16x32_bf16(a0, b0,  acc[0][0], 0, 0, 0);
            acc[0][1] = __builtin_amdgcn_mfma_f32_16x16x32_bf16(a0, b1f, acc[0][1], 0, 0, 0);
            acc[0][2] = __builtin_amdgcn_mfma_f32_16x16x32_bf16(a0, b2f, acc[0][2], 0, 0, 0);
            acc[0][3] = __builtin_amdgcn_mfma_f32_16x16x32_bf16(a0, b3f, acc[0][3], 0, 0, 0);
            acc[1][0] = __builtin_amdgcn_mfma_f32_16x16x32_bf16(a1, b0,  acc[1][0], 0, 0, 0);
            acc[1][1] = __builtin_amdgcn_mfma_f32_16x16x32_bf16(a1, b1f, acc[1][1], 0, 0, 0);
            acc[1][2] = __builtin_amdgcn_mfma_f32_16x16x32_bf16(a1, b2f, acc[1][2], 0, 0, 0);
            acc[1][3] = __builtin_amdgcn_mfma_f32_16x16x32_bf16(a1, b3f, acc[1][3], 0, 0, 0);
        }

#pragma unroll
        for (int mi = 0; mi < 2; mi++) {
#pragma unroll
            for (int ni = 0; ni < 4; ni++) {
                const int rl = wy * 32 + mi * 16 + q * 4;
                const int c = wx * 64 + ni * 16 + n;
#pragma unroll
                for (int r = 0; r < 4; r++) {
                    float v = acc[mi][ni][r] + b1[c];
                    Hs[rl + r][c] = f2bf(fmaxf(v, 0.f));
                }
            }
        }
    }
    __syncthreads();

    // ---- phase 2: out tile = Hs @ W2t + b2, K=128 ----
    {
        const u16* pB = W2t + (size_t)(wx * 64 + n) * 128 + q * 8;

        f32x4 acc[2][4];
#pragma unroll
        for (int i = 0; i < 2; i++)
#pragma unroll
            for (int j = 0; j < 4; j++) acc[i][j] = f32x4{0.f, 0.f, 0.f, 0.f};

#pragma unroll
        for (int kk = 0; kk < 128; kk += 32) {
            bf16x8 a0 = *(const bf16x8*)&Hs[wy * 32 + n][kk + q * 8];
            bf16x8 a1 = *(const bf16x8*)&Hs[wy * 32 + 16 + n][kk + q * 8];
            bf16x8 b0 = *(const bf16x8*)(pB + kk);
            bf16x8 b1f = *(const bf16x8*)(pB + 16 * 128 + kk);
            bf16x8 b2f = *(const bf16x8*)(pB + 32 * 128 + kk);
            bf16x8 b3f = *(const bf16x8*)(pB + 48 * 128 + kk);
            acc[0][0] = __builtin_amdgcn_mfma_f32_16x16x32_bf16(a0, b0,  acc[0][0], 0, 0, 0);
            acc[0][1] = __builtin_amdgcn_mfma_f32_16x16x32_bf16(a0, b1f, acc[0][1], 0, 0, 0);
            acc[0][2] = __builtin_amdgcn_mfma_f32_16x16x32_bf16(a0, b2f, acc[0][2], 0, 0, 0);
            acc[0][3] = __builtin_amdgcn_mfma_f32_16x16x32_bf16(a0, b3f, acc[0][3], 0, 0, 0);
            acc[1][0] = __builtin_amdgcn_mfma_f32_16x16x32_bf16(a1, b0,  acc[1][0], 0, 0, 0);
            acc[1][1] = __builtin_amdgcn_mfma_f32_16x16x32_bf16(a1, b1f, acc[1][1], 0, 0, 0);
            acc[1][2] = __builtin_amdgcn_mfma_f32_16x16x32_bf16(a1, b2f, acc[1][2], 0, 0, 0);
            acc[1][3] = __builtin_amdgcn_mfma_f32_16x16x32_bf16(a1, b3f, acc[1][3], 0, 0, 0);
        }

#pragma unroll
        for (int mi = 0; mi < 2; mi++) {
#pragma unroll
            for (int ni = 0; ni < 4; ni++) {
                const int rbase = row0 + wy * 32 + mi * 16 + q * 4;
                const int c = wx * 64 + ni * 16 + n;
#pragma unroll
                for (int r = 0; r < 4; r++) {
                    const int rr = rbase + r;
                    if (rr >= Mstore) continue;
                    out[(size_t)rr * 128 + c] = acc[mi][ni][r] + b2[c];
                }
            }
        }
    }
}

extern "C" void kernel_launch(void* const* d_in, const int* in_sizes, int n_in,
                              void* d_out, int out_size, void* d_ws, size_t ws_size,
                              hipStream_t stream) {
    const float* z    = (const float*)d_in[0];
    const float* ew   = (const float*)d_in[1];
    const int*   esrc = (const int*)d_in[2];
    const int*   edst = (const int*)d_in[3];
    const float* Wm   = (const float*)d_in[4];
    const float* bm   = (const float*)d_in[5];
    const float* W1   = (const float*)d_in[6];
    const float* b1   = (const float*)d_in[7];
    const float* W2   = (const float*)d_in[8];
    const float* b2   = (const float*)d_in[9];
    float* out = (float*)d_out;

    const int N  = in_sizes[0] / HID;          // 50000
    const int E  = in_sizes[1];                // 800000
    const int Mp = ((N + 63) / 64) * 64;       // 50048

    // workspace layout
    char* w = (char*)d_ws;
    u16*  Ab      = (u16*)w;      w += (size_t)Mp * 256 * 2;   // [zb | aggb]
    u16*  Pb      = (u16*)w;      w += (size_t)Mp * 256 * 2;   // [zWd | zWs]
    u16*  Wt      = (u16*)w;      w += (size_t)81920 * 2;
    int*  deg     = (int*)w;      w += (size_t)(N + 64) * 4;
    int*  offsets = (int*)w;      w += (size_t)(N + 64) * 4;
    int*  cursor  = (int*)w;      w += (size_t)(N + 64) * 4;
    unsigned* s_ew = (unsigned*)w; w += (size_t)E * 4;

    const int bz = (Mp * 32 + 255) / 256;      // z-cast blocks
    const int bw = (81920 + 255) / 256;        // weight blocks
    const int bh = (E + 255) / 256;            // hist blocks

    hipMemsetAsync(deg, 0, (size_t)N * sizeof(int), stream);
    prep_hist<<<bz + bw + bh, 256, 0, stream>>>(z, Wm, W1, W2, edst, Ab, Wt, deg,
                                                N, Mp, E, bz, bw);
    scan_all<<<(N + 1023) / 1024, 256, 0, stream>>>(deg, offsets, cursor, N, E);
    scatter_kernel<<<(E / 4 + 255) / 256, 256, 0, stream>>>(esrc, edst, ew, cursor, s_ew, E);

    gemm_P<<<Mp / 64, 256, 0, stream>>>(Ab, Wt, Pb, Mp);
    aggregate_kernel<<<(Mp + 3) / 4, 256, 0, stream>>>(Pb, bm, Wm + 256 * 128,
                                                       offsets, s_ew, Ab, N, Mp);
    gemm_HO<<<Mp / 64, 256, 0, stream>>>(Ab, Wt + 32768, b1, Wt + 65536, b2, out, N);
}

// Round 7
// 287.235 us; speedup vs baseline: 2.3031x; 1.0817x over previous
//
#include <hip/hip_runtime.h>
#include <hip/hip_bf16.h>

#define HID 128

typedef short bf16x8 __attribute__((ext_vector_type(8)));
typedef float f32x4  __attribute__((ext_vector_type(4)));
typedef unsigned short u16;
typedef unsigned long long u64;

__device__ __forceinline__ u16 f2bf(float f) {
    __hip_bfloat16 h = __float2bfloat16(f);
    return *reinterpret_cast<u16*>(&h);
}
__device__ __forceinline__ float bf2f(u16 x) {
    unsigned u = ((unsigned)x) << 16;
    return __uint_as_float(u);
}
// record: dst(17b)<<31 | src(16b)<<15 | wq(15b); low 31 bits = final s_ew record
__device__ __forceinline__ u64 pack_rec(int dst, int src, float w) {
    int wq = (int)fmaf(w, 32768.f, 0.5f);
    wq = wq > 32767 ? 32767 : wq;
    return ((u64)(unsigned)dst << 31) | ((unsigned)src << 15) | (unsigned)wq;
}

// Wt layout (u16): [0,32768) Wds^T (256 rows x 128k: Wd^T then Ws^T)
//                  [32768,65536) W1^T (128 rows x 256k)
//                  [65536,81920) W2^T (128 rows x 128k)

// ---------- fused prep (z-cast + weight transpose/cast) + edge histogram ----------
__global__ __launch_bounds__(256)
void prep_hist(const float* __restrict__ z, const float* __restrict__ Wm,
               const float* __restrict__ W1, const float* __restrict__ W2,
               const int* __restrict__ edst,
               u16* __restrict__ Ab, u16* __restrict__ Wt, int* __restrict__ deg,
               int N, int Mp, int E, int bz, int bw)
{
    const int b = blockIdx.x;
    const int t = threadIdx.x;
    if (b < bz) {
        const int idx4 = (b * 256 + t) * 4;
        if (idx4 >= Mp * 128) return;
        const int row = idx4 >> 7, col = idx4 & 127;
        ushort4 u;
        if (row < N) {
            const float4 v = *(const float4*)&z[(size_t)row * 128 + col];
            u.x = f2bf(v.x); u.y = f2bf(v.y); u.z = f2bf(v.z); u.w = f2bf(v.w);
        } else { u.x = 0; u.y = 0; u.z = 0; u.w = 0; }
        *(ushort4*)&Ab[(size_t)row * 256 + col] = u;
    } else if (b < bz + bw) {
        const int idx = (b - bz) * 256 + t;
        if (idx >= 81920) return;
        float v;
        if (idx < 32768) {
            const int nn = idx >> 7, k = idx & 127;
            v = (nn < 128) ? Wm[k * 128 + nn] : Wm[(128 + k) * 128 + (nn - 128)];
        } else if (idx < 65536) {
            const int j = idx - 32768, n = j >> 8, k = j & 255;
            v = W1[k * 128 + n];
        } else {
            const int j = idx - 65536, n = j >> 7, k = j & 127;
            v = W2[k * 128 + n];
        }
        Wt[idx] = f2bf(v);
    } else {
        const int e = (b - bz - bw) * 256 + t;
        if (e < E) atomicAdd(&deg[edst[e]], 1);
    }
}

// ---------- single-kernel exclusive scan; also seeds bucket cursors ----------
__global__ __launch_bounds__(256)
void scan_all(const int* __restrict__ deg, int* __restrict__ offsets,
              int* __restrict__ bcur, int N, int E)
{
    __shared__ int ps[256];
    __shared__ int red[4];
    const int t = threadIdx.x;
    const int base0 = blockIdx.x * 1024;

    int pre = 0;
    for (int i = t; i < base0; i += 256) pre += deg[i];
    int s = pre;
#pragma unroll
    for (int off = 32; off > 0; off >>= 1) s += __shfl_down(s, off);
    if ((t & 63) == 0) red[t >> 6] = s;
    __syncthreads();
    const int block_pre = red[0] + red[1] + red[2] + red[3];

    const int base = base0 + t * 4;
    int d[4]; int ls = 0;
#pragma unroll
    for (int j = 0; j < 4; j++) { int i = base + j; d[j] = (i < N) ? deg[i] : 0; ls += d[j]; }
    __syncthreads();
    ps[t] = ls;
    __syncthreads();
    for (int off = 1; off < 256; off <<= 1) {
        int add = (t >= off) ? ps[t - off] : 0;
        __syncthreads();
        ps[t] += add;
        __syncthreads();
    }
    int run = ps[t] - ls + block_pre;
#pragma unroll
    for (int j = 0; j < 4; j++) {
        int i = base + j;
        if (i < N) {
            offsets[i] = run;
            if ((i & 511) == 0) bcur[i >> 9] = run;   // bucket cursor seed
        }
        run += d[j];
    }
    if (blockIdx.x == 0 && t == 0) offsets[N] = E;
}

// ---------- pass 1: scatter u64 records into bucket-major order ----------
// 4096 edges/block; per-(block,bucket) contiguous runs -> dense 8B writes.
__global__ __launch_bounds__(256)
void bucket_scatter(const int* __restrict__ esrc, const int* __restrict__ edst,
                    const float* __restrict__ ew, int* __restrict__ bcur,
                    u64* __restrict__ tmp, int E, int nbk)
{
    __shared__ int cnt[256];
    __shared__ int rbase[256];
    const int t = threadIdx.x;
    const int e0 = blockIdx.x * 4096;
    const int eend = min(e0 + 4096, E);

    cnt[t] = 0;
    __syncthreads();

    if (eend - e0 == 4096) {               // full block: cache records in regs
        int myb[16]; u64 myrec[16];
#pragma unroll
        for (int i = 0; i < 16; i++) {
            const int e = e0 + t + i * 256;
            const int d = edst[e];
            myb[i] = d >> 9;
            myrec[i] = pack_rec(d, esrc[e], ew[e]);
            atomicAdd(&cnt[myb[i]], 1);
        }
        __syncthreads();
        if (cnt[t] > 0) rbase[t] = atomicAdd(&bcur[t], cnt[t]);
        __syncthreads();
        cnt[t] = 0;
        __syncthreads();
#pragma unroll
        for (int i = 0; i < 16; i++) {
            const int r = atomicAdd(&cnt[myb[i]], 1);
            tmp[(size_t)rbase[myb[i]] + r] = myrec[i];
        }
    } else {                               // tail block: recompute
        for (int e = e0 + t; e < eend; e += 256)
            atomicAdd(&cnt[edst[e] >> 9], 1);
        __syncthreads();
        if (cnt[t] > 0) rbase[t] = atomicAdd(&bcur[t], cnt[t]);
        __syncthreads();
        cnt[t] = 0;
        __syncthreads();
        for (int e = e0 + t; e < eend; e += 256) {
            const int d = edst[e];
            const int b = d >> 9;
            const int r = atomicAdd(&cnt[b], 1);
            tmp[(size_t)rbase[b] + r] = pack_rec(d, esrc[e], ew[e]);
        }
    }
}

// ---------- pass 2: within-bucket counting sort -> final CSR stream ----------
// one block per bucket; output span contiguous (~32KB) -> stays in one L2.
__global__ __launch_bounds__(256)
void bucket_sort(const u64* __restrict__ tmp, const int* __restrict__ offsets,
                 unsigned* __restrict__ s_ew, int N, int nbk)
{
    __shared__ int cur[512];
    const int b = blockIdx.x;
    const int n0 = b << 9;
    const int nhi = min(512, N - n0);
    const int t = threadIdx.x;
    for (int i = t; i < nhi; i += 256) cur[i] = offsets[n0 + i];
    __syncthreads();
    const int base = offsets[n0];
    const int endp = offsets[min(n0 + 512, N)];
    for (int r = base + t; r < endp; r += 256) {
        const u64 rec = tmp[r];
        const int local = (int)(rec >> 31) - n0;
        const int pos = atomicAdd(&cur[local], 1);
        s_ew[pos] = (unsigned)(rec & 0x7FFFFFFFu);
    }
}

// ---------- Pb = z @ [Wd | Ws]  (64 rows x 256 cols per block, K=128) ----------
__global__ __launch_bounds__(256)
void gemm_P(const u16* __restrict__ Ab, const u16* __restrict__ Wds_t,
            u16* __restrict__ Pb, int Mp)
{
    const int row0 = blockIdx.x * 64;
    const int tid = threadIdx.x;
    const int wv = tid >> 6, lane = tid & 63;
    const int wy = wv & 1, wx = wv >> 1;
    const int q = lane >> 4, n = lane & 15;

    const u16* pA = Ab + (size_t)(row0 + wy * 32 + n) * 256 + q * 8;
    const u16* pB = Wds_t + (size_t)(wx * 128 + n) * 128 + q * 8;

    f32x4 acc[2][8];
#pragma unroll
    for (int i = 0; i < 2; i++)
#pragma unroll
        for (int j = 0; j < 8; j++) acc[i][j] = f32x4{0.f, 0.f, 0.f, 0.f};

#pragma unroll
    for (int kk = 0; kk < 128; kk += 32) {
        bf16x8 a0 = *(const bf16x8*)(pA + kk);
        bf16x8 a1 = *(const bf16x8*)(pA + 16 * 256 + kk);
        bf16x8 bfr[8];
#pragma unroll
        for (int ni = 0; ni < 8; ni++)
            bfr[ni] = *(const bf16x8*)(pB + (size_t)ni * 16 * 128 + kk);
#pragma unroll
        for (int ni = 0; ni < 8; ni++) {
            acc[0][ni] = __builtin_amdgcn_mfma_f32_16x16x32_bf16(a0, bfr[ni], acc[0][ni], 0, 0, 0);
            acc[1][ni] = __builtin_amdgcn_mfma_f32_16x16x32_bf16(a1, bfr[ni], acc[1][ni], 0, 0, 0);
        }
    }

#pragma unroll
    for (int mi = 0; mi < 2; mi++) {
#pragma unroll
        for (int ni = 0; ni < 8; ni++) {
            const int rbase = row0 + wy * 32 + mi * 16 + q * 4;
            const int c = wx * 128 + ni * 16 + n;
#pragma unroll
            for (int r = 0; r < 4; r++)
                Pb[(size_t)(rbase + r) * 256 + c] = f2bf(acc[mi][ni][r]);
        }
    }
}

// ---------- per-node segmented max + finalize -> Ab agg slice ----------
__global__ __launch_bounds__(256)
void aggregate_kernel(const u16* __restrict__ Pb,
                      const float* __restrict__ bm,
                      const float* __restrict__ ww,
                      const int* __restrict__ offsets,
                      const unsigned* __restrict__ s_ew,
                      u16* __restrict__ Ab, int N, int Mp)
{
    const int t = threadIdx.x;
    const int lane = t & 63;
    const int nd = blockIdx.x * 4 + (t >> 6);
    if (nd >= Mp) return;
    const int h0 = lane * 2;
    u16* dst = &Ab[(size_t)nd * 256 + 128 + h0];
    if (nd >= N) { *(ushort2*)dst = make_ushort2(0, 0); return; }

    const int start = offsets[nd];       // wave-uniform
    const int end   = offsets[nd + 1];
    const float ww0 = ww[h0], ww1 = ww[h0 + 1];
    const float kq = 1.f / 32768.f;
    float m0 = -INFINITY, m1 = -INFINITY;

    int e = start;
    for (; e + 3 < end; e += 4) {
        const unsigned u0 = s_ew[e],     u1 = s_ew[e + 1];
        const unsigned u2 = s_ew[e + 2], u3 = s_ew[e + 3];
        const float w0 = (float)(u0 & 32767u) * kq;
        const float w1 = (float)(u1 & 32767u) * kq;
        const float w2 = (float)(u2 & 32767u) * kq;
        const float w3 = (float)(u3 & 32767u) * kq;
        const ushort2 z0 = *(const ushort2*)&Pb[(size_t)(u0 >> 15) * 256 + 128 + h0];
        const ushort2 z1 = *(const ushort2*)&Pb[(size_t)(u1 >> 15) * 256 + 128 + h0];
        const ushort2 z2 = *(const ushort2*)&Pb[(size_t)(u2 >> 15) * 256 + 128 + h0];
        const ushort2 z3 = *(const ushort2*)&Pb[(size_t)(u3 >> 15) * 256 + 128 + h0];
        const float a0 = fmaf(w0, ww0, bf2f(z0.x)), c0 = fmaf(w0, ww1, bf2f(z0.y));
        const float a1 = fmaf(w1, ww0, bf2f(z1.x)), c1 = fmaf(w1, ww1, bf2f(z1.y));
        const float a2 = fmaf(w2, ww0, bf2f(z2.x)), c2 = fmaf(w2, ww1, bf2f(z2.y));
        const float a3 = fmaf(w3, ww0, bf2f(z3.x)), c3 = fmaf(w3, ww1, bf2f(z3.y));
        m0 = fmaxf(m0, fmaxf(fmaxf(a0, a1), fmaxf(a2, a3)));
        m1 = fmaxf(m1, fmaxf(fmaxf(c0, c1), fmaxf(c2, c3)));
    }
    for (; e < end; e++) {
        const unsigned u0 = s_ew[e];
        const float w0 = (float)(u0 & 32767u) * kq;
        const ushort2 z0 = *(const ushort2*)&Pb[(size_t)(u0 >> 15) * 256 + 128 + h0];
        m0 = fmaxf(m0, fmaf(w0, ww0, bf2f(z0.x)));
        m1 = fmaxf(m1, fmaf(w0, ww1, bf2f(z0.y)));
    }

    ushort2 outv;
    if (end > start) {
        const ushort2 zd = *(const ushort2*)&Pb[(size_t)nd * 256 + h0];
        outv.x = f2bf(bf2f(zd.x) + bm[h0]     + m0);
        outv.y = f2bf(bf2f(zd.y) + bm[h0 + 1] + m1);
    } else { outv.x = 0; outv.y = 0; }
    *(ushort2*)dst = outv;
}

// ---------- fused: H = relu([z|agg]@W1+b1) (K=256) -> LDS -> out = H@W2+b2 ----------
__global__ __launch_bounds__(256)
void gemm_HO(const u16* __restrict__ Ab, const u16* __restrict__ W1t,
             const float* __restrict__ b1, const u16* __restrict__ W2t,
             const float* __restrict__ b2, float* __restrict__ out, int Mstore)
{
    __shared__ u16 Hs[64][136];

    const int row0 = blockIdx.x * 64;
    const int tid = threadIdx.x;
    const int wv = tid >> 6, lane = tid & 63;
    const int wy = wv & 1, wx = wv >> 1;
    const int q = lane >> 4, n = lane & 15;

    {
        const u16* pA = Ab + (size_t)(row0 + wy * 32 + n) * 256 + q * 8;
        const u16* pB = W1t + (size_t)(wx * 64 + n) * 256 + q * 8;

        f32x4 acc[2][4];
#pragma unroll
        for (int i = 0; i < 2; i++)
#pragma unroll
            for (int j = 0; j < 4; j++) acc[i][j] = f32x4{0.f, 0.f, 0.f, 0.f};

#pragma unroll
        for (int kk = 0; kk < 256; kk += 32) {
            bf16x8 a0 = *(const bf16x8*)(pA + kk);
            bf16x8 a1 = *(const bf16x8*)(pA + 16 * 256 + kk);
            bf16x8 b0 = *(const bf16x8*)(pB + kk);
            bf16x8 b1f = *(const bf16x8*)(pB + 16 * 256 + kk);
            bf16x8 b2f = *(const bf16x8*)(pB + 32 * 256 + kk);
            bf16x8 b3f = *(const bf16x8*)(pB + 48 * 256 + kk);
            acc[0][0] = __builtin_amdgcn_mfma_f32_16x16x32_bf16(a0, b0,  acc[0][0], 0, 0, 0);
            acc[0][1] = __builtin_amdgcn_mfma_f32_16x16x32_bf16(a0, b1f, acc[0][1], 0, 0, 0);
            acc[0][2] = __builtin_amdgcn_mfma_f32_16x16x32_bf16(a0, b2f, acc[0][2], 0, 0, 0);
            acc[0][3] = __builtin_amdgcn_mfma_f32_16x16x32_bf16(a0, b3f, acc[0][3], 0, 0, 0);
            acc[1][0] = __builtin_amdgcn_mfma_f32_16x16x32_bf16(a1, b0,  acc[1][0], 0, 0, 0);
            acc[1][1] = __builtin_amdgcn_mfma_f32_16x16x32_bf16(a1, b1f, acc[1][1], 0, 0, 0);
            acc[1][2] = __builtin_amdgcn_mfma_f32_16x16x32_bf16(a1, b2f, acc[1][2], 0, 0, 0);
            acc[1][3] = __builtin_amdgcn_mfma_f32_16x16x32_bf16(a1, b3f, acc[1][3], 0, 0, 0);
        }

#pragma unroll
        for (int mi = 0; mi < 2; mi++) {
#pragma unroll
            for (int ni = 0; ni < 4; ni++) {
                const int rl = wy * 32 + mi * 16 + q * 4;
                const int c = wx * 64 + ni * 16 + n;
#pragma unroll
                for (int r = 0; r < 4; r++) {
                    float v = acc[mi][ni][r] + b1[c];
                    Hs[rl + r][c] = f2bf(fmaxf(v, 0.f));
                }
            }
        }
    }
    __syncthreads();

    {
        const u16* pB = W2t + (size_t)(wx * 64 + n) * 128 + q * 8;

        f32x4 acc[2][4];
#pragma unroll
        for (int i = 0; i < 2; i++)
#pragma unroll
            for (int j = 0; j < 4; j++) acc[i][j] = f32x4{0.f, 0.f, 0.f, 0.f};

#pragma unroll
        for (int kk = 0; kk < 128; kk += 32) {
            bf16x8 a0 = *(const bf16x8*)&Hs[wy * 32 + n][kk + q * 8];
            bf16x8 a1 = *(const bf16x8*)&Hs[wy * 32 + 16 + n][kk + q * 8];
            bf16x8 b0 = *(const bf16x8*)(pB + kk);
            bf16x8 b1f = *(const bf16x8*)(pB + 16 * 128 + kk);
            bf16x8 b2f = *(const bf16x8*)(pB + 32 * 128 + kk);
            bf16x8 b3f = *(const bf16x8*)(pB + 48 * 128 + kk);
            acc[0][0] = __builtin_amdgcn_mfma_f32_16x16x32_bf16(a0, b0,  acc[0][0], 0, 0, 0);
            acc[0][1] = __builtin_amdgcn_mfma_f32_16x16x32_bf16(a0, b1f, acc[0][1], 0, 0, 0);
            acc[0][2] = __builtin_amdgcn_mfma_f32_16x16x32_bf16(a0, b2f, acc[0][2], 0, 0, 0);
            acc[0][3] = __builtin_amdgcn_mfma_f32_16x16x32_bf16(a0, b3f, acc[0][3], 0, 0, 0);
            acc[1][0] = __builtin_amdgcn_mfma_f32_16x16x32_bf16(a1, b0,  acc[1][0], 0, 0, 0);
            acc[1][1] = __builtin_amdgcn_mfma_f32_16x16x32_bf16(a1, b1f, acc[1][1], 0, 0, 0);
            acc[1][2] = __builtin_amdgcn_mfma_f32_16x16x32_bf16(a1, b2f, acc[1][2], 0, 0, 0);
            acc[1][3] = __builtin_amdgcn_mfma_f32_16x16x32_bf16(a1, b3f, acc[1][3], 0, 0, 0);
        }

#pragma unroll
        for (int mi = 0; mi < 2; mi++) {
#pragma unroll
            for (int ni = 0; ni < 4; ni++) {
                const int rbase = row0 + wy * 32 + mi * 16 + q * 4;
                const int c = wx * 64 + ni * 16 + n;
#pragma unroll
                for (int r = 0; r < 4; r++) {
                    const int rr = rbase + r;
                    if (rr >= Mstore) continue;
                    out[(size_t)rr * 128 + c] = acc[mi][ni][r] + b2[c];
                }
            }
        }
    }
}

extern "C" void kernel_launch(void* const* d_in, const int* in_sizes, int n_in,
                              void* d_out, int out_size, void* d_ws, size_t ws_size,
                              hipStream_t stream) {
    const float* z    = (const float*)d_in[0];
    const float* ew   = (const float*)d_in[1];
    const int*   esrc = (const int*)d_in[2];
    const int*   edst = (const int*)d_in[3];
    const float* Wm   = (const float*)d_in[4];
    const float* bm   = (const float*)d_in[5];
    const float* W1   = (const float*)d_in[6];
    const float* b1   = (const float*)d_in[7];
    const float* W2   = (const float*)d_in[8];
    const float* b2   = (const float*)d_in[9];
    float* out = (float*)d_out;

    const int N  = in_sizes[0] / HID;          // 50000
    const int E  = in_sizes[1];                // 800000
    const int Mp = ((N + 63) / 64) * 64;       // 50048
    const int nbk = (N + 511) / 512;           // 98 buckets

    // workspace layout
    char* w = (char*)d_ws;
    u16*  Ab      = (u16*)w;      w += (size_t)Mp * 256 * 2;   // [zb | aggb]
    u16*  Pb      = (u16*)w;      w += (size_t)Mp * 256 * 2;   // [zWd | zWs]; tmp aliases
    u16*  Wt      = (u16*)w;      w += (size_t)81920 * 2;
    int*  deg     = (int*)w;      w += (size_t)(N + 64) * 4;
    int*  offsets = (int*)w;      w += (size_t)(N + 64) * 4;
    int*  bcur    = (int*)w;      w += 256 * 4;
    unsigned* s_ew = (unsigned*)w; w += (size_t)E * 4;

    u64* tmp = (u64*)Pb;   // 6.4 MB, consumed by bucket_sort before gemm_P writes Pb

    const int bz = (Mp * 32 + 255) / 256;
    const int bw = (81920 + 255) / 256;
    const int bh = (E + 255) / 256;

    hipMemsetAsync(deg, 0, (size_t)N * sizeof(int), stream);
    prep_hist<<<bz + bw + bh, 256, 0, stream>>>(z, Wm, W1, W2, edst, Ab, Wt, deg,
                                                N, Mp, E, bz, bw);
    scan_all<<<(N + 1023) / 1024, 256, 0, stream>>>(deg, offsets, bcur, N, E);
    bucket_scatter<<<(E + 4095) / 4096, 256, 0, stream>>>(esrc, edst, ew, bcur, tmp, E, nbk);
    bucket_sort<<<nbk, 256, 0, stream>>>(tmp, offsets, s_ew, N, nbk);

    gemm_P<<<Mp / 64, 256, 0, stream>>>(Ab, Wt, Pb, Mp);
    aggregate_kernel<<<(Mp + 3) / 4, 256, 0, stream>>>(Pb, bm, Wm + 256 * 128,
                                                       offsets, s_ew, Ab, N, Mp);
    gemm_HO<<<Mp / 64, 256, 0, stream>>>(Ab, Wt + 32768, b1, Wt + 65536, b2, out, N);
}

// Round 8
// 251.856 us; speedup vs baseline: 2.6267x; 1.1405x over previous
//
#include <hip/hip_runtime.h>
#include <hip/hip_bf16.h>

#define HID 128

typedef short bf16x8 __attribute__((ext_vector_type(8)));
typedef float f32x4  __attribute__((ext_vector_type(4)));
typedef unsigned short u16;
typedef unsigned long long u64;

__device__ __forceinline__ u16 f2bf(float f) {
    __hip_bfloat16 h = __float2bfloat16(f);
    return *reinterpret_cast<u16*>(&h);
}
__device__ __forceinline__ float bf2f(u16 x) {
    unsigned u = ((unsigned)x) << 16;
    return __uint_as_float(u);
}
// record: dst(17b)<<31 | src(16b)<<15 | wq(15b); low 31 bits = final s_ew record
__device__ __forceinline__ u64 pack_rec(int dst, int src, float w) {
    int wq = (int)fmaf(w, 32768.f, 0.5f);
    wq = wq > 32767 ? 32767 : wq;
    return ((u64)(unsigned)dst << 31) | ((unsigned)src << 15) | (unsigned)wq;
}

// Wt layout (u16): [0,32768) Wds^T (256 rows x 128k: Wd^T then Ws^T)
//                  [32768,65536) W1^T (128 rows x 256k)
//                  [65536,81920) W2^T (128 rows x 128k)

// ---------- fused prep (z-cast + weight transpose/cast) + COARSE histogram ----------
__global__ __launch_bounds__(256)
void prep_hist(const float* __restrict__ z, const float* __restrict__ Wm,
               const float* __restrict__ W1, const float* __restrict__ W2,
               const int* __restrict__ edst,
               u16* __restrict__ Ab, u16* __restrict__ Wt, int* __restrict__ bhist,
               int N, int Mp, int E, int bz, int bw, int nbk)
{
    __shared__ int lh[128];
    const int b = blockIdx.x;
    const int t = threadIdx.x;
    if (b < bz) {
        const int idx4 = (b * 256 + t) * 4;
        if (idx4 >= Mp * 128) return;
        const int row = idx4 >> 7, col = idx4 & 127;
        ushort4 u;
        if (row < N) {
            const float4 v = *(const float4*)&z[(size_t)row * 128 + col];
            u.x = f2bf(v.x); u.y = f2bf(v.y); u.z = f2bf(v.z); u.w = f2bf(v.w);
        } else { u.x = 0; u.y = 0; u.z = 0; u.w = 0; }
        *(ushort4*)&Ab[(size_t)row * 256 + col] = u;
    } else if (b < bz + bw) {
        const int idx = (b - bz) * 256 + t;
        if (idx >= 81920) return;
        float v;
        if (idx < 32768) {
            const int nn = idx >> 7, k = idx & 127;
            v = (nn < 128) ? Wm[k * 128 + nn] : Wm[(128 + k) * 128 + (nn - 128)];
        } else if (idx < 65536) {
            const int j = idx - 32768, n = j >> 8, k = j & 255;
            v = W1[k * 128 + n];
        } else {
            const int j = idx - 65536, n = j >> 7, k = j & 127;
            v = W2[k * 128 + n];
        }
        Wt[idx] = f2bf(v);
    } else {
        // coarse histogram: 4096 edges/block, LDS-reduced
        if (t < 128) lh[t] = 0;
        __syncthreads();
        const int e0 = (b - bz - bw) * 4096;
        const int eend = min(e0 + 4096, E);
        for (int e = e0 + t; e < eend; e += 256)
            atomicAdd(&lh[edst[e] >> 9], 1);
        __syncthreads();
        if (t < nbk && lh[t] > 0) atomicAdd(&bhist[t], lh[t]);
    }
}

// ---------- pass 1: scatter u64 records into bucket-major order ----------
__global__ __launch_bounds__(256)
void bucket_scatter(const int* __restrict__ esrc, const int* __restrict__ edst,
                    const float* __restrict__ ew,
                    const int* __restrict__ bhist, int* __restrict__ brun,
                    u64* __restrict__ tmp, int E, int nbk)
{
    __shared__ int cnt[128];
    __shared__ int rbase[128];
    __shared__ int bbase[128];
    const int t = threadIdx.x;
    const int e0 = blockIdx.x * 4096;
    const int eend = min(e0 + 4096, E);

    if (t < 128) cnt[t] = 0;
    if (t == 0) {                       // serial 98-prefix: cheap, block-local
        int run = 0;
        for (int i = 0; i < nbk; i++) { bbase[i] = run; run += bhist[i]; }
    }
    __syncthreads();

    if (eend - e0 == 4096) {
        int myb[16]; u64 myrec[16];
#pragma unroll
        for (int i = 0; i < 16; i++) {
            const int e = e0 + t + i * 256;
            const int d = edst[e];
            myb[i] = d >> 9;
            myrec[i] = pack_rec(d, esrc[e], ew[e]);
            atomicAdd(&cnt[myb[i]], 1);
        }
        __syncthreads();
        if (t < nbk && cnt[t] > 0) rbase[t] = bbase[t] + atomicAdd(&brun[t], cnt[t]);
        __syncthreads();
        if (t < 128) cnt[t] = 0;
        __syncthreads();
#pragma unroll
        for (int i = 0; i < 16; i++) {
            const int r = atomicAdd(&cnt[myb[i]], 1);
            tmp[(size_t)rbase[myb[i]] + r] = myrec[i];
        }
    } else {
        for (int e = e0 + t; e < eend; e += 256)
            atomicAdd(&cnt[edst[e] >> 9], 1);
        __syncthreads();
        if (t < nbk && cnt[t] > 0) rbase[t] = bbase[t] + atomicAdd(&brun[t], cnt[t]);
        __syncthreads();
        if (t < 128) cnt[t] = 0;
        __syncthreads();
        for (int e = e0 + t; e < eend; e += 256) {
            const int d = edst[e];
            const int bk = d >> 9;
            const int r = atomicAdd(&cnt[bk], 1);
            tmp[(size_t)rbase[bk] + r] = pack_rec(d, esrc[e], ew[e]);
        }
    }
}

// ---------- pass 2: within-bucket degree count + scan + counting sort ----------
// one block per bucket; writes CSR offsets AND the final sorted stream.
__global__ __launch_bounds__(256)
void bucket_sort(const u64* __restrict__ tmp, const int* __restrict__ bhist,
                 int* __restrict__ offsets, unsigned* __restrict__ s_ew,
                 int N, int E, int nbk)
{
    __shared__ int cnt[512];
    __shared__ int cur[512];
    __shared__ int ps[256];
    __shared__ int sh_base[2];
    const int b = blockIdx.x;
    const int t = threadIdx.x;
    const int n0 = b << 9;
    const int nhi = min(512, N - n0);

    if (t == 0) {
        int run = 0;
        for (int i = 0; i < b; i++) run += bhist[i];
        sh_base[0] = run;
        sh_base[1] = run + bhist[b];
    }
    cnt[t] = 0; cnt[t + 256] = 0;
    __syncthreads();
    const int base = sh_base[0];
    const int endp = sh_base[1];

    // count per-node degrees from this bucket's contiguous records
    for (int r = base + t; r < endp; r += 256)
        atomicAdd(&cnt[(int)(tmp[r] >> 31) - n0], 1);
    __syncthreads();

    // exclusive scan of 512 in LDS
    const int a0 = cnt[2 * t], a1 = cnt[2 * t + 1];
    const int sp = a0 + a1;
    ps[t] = sp;
    __syncthreads();
    for (int off = 1; off < 256; off <<= 1) {
        int add = (t >= off) ? ps[t - off] : 0;
        __syncthreads();
        ps[t] += add;
        __syncthreads();
    }
    const int ex = ps[t] - sp;
    cur[2 * t]     = base + ex;
    cur[2 * t + 1] = base + ex + a0;
    __syncthreads();

    // publish CSR offsets
    for (int i = t; i < nhi; i += 256) offsets[n0 + i] = cur[i];
    if (t == 0 && n0 + nhi == N) offsets[N] = E;

    // scatter into final CSR stream (contiguous ~32KB span -> L2-local)
    for (int r = base + t; r < endp; r += 256) {
        const u64 rec = tmp[r];
        const int local = (int)(rec >> 31) - n0;
        const int pos = atomicAdd(&cur[local], 1);
        s_ew[pos] = (unsigned)(rec & 0x7FFFFFFFu);
    }
}

// ---------- Pb = z @ [Wd | Ws]  (64 rows x 256 cols per block, K=128) ----------
__global__ __launch_bounds__(256)
void gemm_P(const u16* __restrict__ Ab, const u16* __restrict__ Wds_t,
            u16* __restrict__ Pb, int Mp)
{
    const int row0 = blockIdx.x * 64;
    const int tid = threadIdx.x;
    const int wv = tid >> 6, lane = tid & 63;
    const int wy = wv & 1, wx = wv >> 1;
    const int q = lane >> 4, n = lane & 15;

    const u16* pA = Ab + (size_t)(row0 + wy * 32 + n) * 256 + q * 8;
    const u16* pB = Wds_t + (size_t)(wx * 128 + n) * 128 + q * 8;

    f32x4 acc[2][8];
#pragma unroll
    for (int i = 0; i < 2; i++)
#pragma unroll
        for (int j = 0; j < 8; j++) acc[i][j] = f32x4{0.f, 0.f, 0.f, 0.f};

#pragma unroll
    for (int kk = 0; kk < 128; kk += 32) {
        bf16x8 a0 = *(const bf16x8*)(pA + kk);
        bf16x8 a1 = *(const bf16x8*)(pA + 16 * 256 + kk);
        bf16x8 bfr[8];
#pragma unroll
        for (int ni = 0; ni < 8; ni++)
            bfr[ni] = *(const bf16x8*)(pB + (size_t)ni * 16 * 128 + kk);
#pragma unroll
        for (int ni = 0; ni < 8; ni++) {
            acc[0][ni] = __builtin_amdgcn_mfma_f32_16x16x32_bf16(a0, bfr[ni], acc[0][ni], 0, 0, 0);
            acc[1][ni] = __builtin_amdgcn_mfma_f32_16x16x32_bf16(a1, bfr[ni], acc[1][ni], 0, 0, 0);
        }
    }

#pragma unroll
    for (int mi = 0; mi < 2; mi++) {
#pragma unroll
        for (int ni = 0; ni < 8; ni++) {
            const int rbase = row0 + wy * 32 + mi * 16 + q * 4;
            const int c = wx * 128 + ni * 16 + n;
#pragma unroll
            for (int r = 0; r < 4; r++)
                Pb[(size_t)(rbase + r) * 256 + c] = f2bf(acc[mi][ni][r]);
        }
    }
}

// ---------- per-node segmented max + finalize -> Ab agg slice ----------
__global__ __launch_bounds__(256)
void aggregate_kernel(const u16* __restrict__ Pb,
                      const float* __restrict__ bm,
                      const float* __restrict__ ww,
                      const int* __restrict__ offsets,
                      const unsigned* __restrict__ s_ew,
                      u16* __restrict__ Ab, int N, int Mp)
{
    const int t = threadIdx.x;
    const int lane = t & 63;
    const int nd = blockIdx.x * 4 + (t >> 6);
    if (nd >= Mp) return;
    const int h0 = lane * 2;
    u16* dst = &Ab[(size_t)nd * 256 + 128 + h0];
    if (nd >= N) { *(ushort2*)dst = make_ushort2(0, 0); return; }

    const int start = offsets[nd];       // wave-uniform
    const int end   = offsets[nd + 1];
    const float ww0 = ww[h0], ww1 = ww[h0 + 1];
    const float kq = 1.f / 32768.f;
    float m0 = -INFINITY, m1 = -INFINITY;

    int e = start;
    for (; e + 3 < end; e += 4) {
        const unsigned u0 = s_ew[e],     u1 = s_ew[e + 1];
        const unsigned u2 = s_ew[e + 2], u3 = s_ew[e + 3];
        const float w0 = (float)(u0 & 32767u) * kq;
        const float w1 = (float)(u1 & 32767u) * kq;
        const float w2 = (float)(u2 & 32767u) * kq;
        const float w3 = (float)(u3 & 32767u) * kq;
        const ushort2 z0 = *(const ushort2*)&Pb[(size_t)(u0 >> 15) * 256 + 128 + h0];
        const ushort2 z1 = *(const ushort2*)&Pb[(size_t)(u1 >> 15) * 256 + 128 + h0];
        const ushort2 z2 = *(const ushort2*)&Pb[(size_t)(u2 >> 15) * 256 + 128 + h0];
        const ushort2 z3 = *(const ushort2*)&Pb[(size_t)(u3 >> 15) * 256 + 128 + h0];
        const float a0 = fmaf(w0, ww0, bf2f(z0.x)), c0 = fmaf(w0, ww1, bf2f(z0.y));
        const float a1 = fmaf(w1, ww0, bf2f(z1.x)), c1 = fmaf(w1, ww1, bf2f(z1.y));
        const float a2 = fmaf(w2, ww0, bf2f(z2.x)), c2 = fmaf(w2, ww1, bf2f(z2.y));
        const float a3 = fmaf(w3, ww0, bf2f(z3.x)), c3 = fmaf(w3, ww1, bf2f(z3.y));
        m0 = fmaxf(m0, fmaxf(fmaxf(a0, a1), fmaxf(a2, a3)));
        m1 = fmaxf(m1, fmaxf(fmaxf(c0, c1), fmaxf(c2, c3)));
    }
    for (; e < end; e++) {
        const unsigned u0 = s_ew[e];
        const float w0 = (float)(u0 & 32767u) * kq;
        const ushort2 z0 = *(const ushort2*)&Pb[(size_t)(u0 >> 15) * 256 + 128 + h0];
        m0 = fmaxf(m0, fmaf(w0, ww0, bf2f(z0.x)));
        m1 = fmaxf(m1, fmaf(w0, ww1, bf2f(z0.y)));
    }

    ushort2 outv;
    if (end > start) {
        const ushort2 zd = *(const ushort2*)&Pb[(size_t)nd * 256 + h0];
        outv.x = f2bf(bf2f(zd.x) + bm[h0]     + m0);
        outv.y = f2bf(bf2f(zd.y) + bm[h0 + 1] + m1);
    } else { outv.x = 0; outv.y = 0; }
    *(ushort2*)dst = outv;
}

// ---------- fused: H = relu([z|agg]@W1+b1) (K=256) -> LDS -> out = H@W2+b2 ----------
// 32-row tiles -> 2x the blocks of the 64-row version (grid was occupancy-starved).
__global__ __launch_bounds__(256)
void gemm_HO(const u16* __restrict__ Ab, const u16* __restrict__ W1t,
             const float* __restrict__ b1, const u16* __restrict__ W2t,
             const float* __restrict__ b2, float* __restrict__ out, int Mstore)
{
    __shared__ u16 Hs[32][136];

    const int row0 = blockIdx.x * 32;
    const int tid = threadIdx.x;
    const int wv = tid >> 6, lane = tid & 63;
    const int wy = wv & 1, wx = wv >> 1;   // wave = 16 rows x 64 cols
    const int q = lane >> 4, n = lane & 15;

    // ---- phase 1: H tile (32 x 128), K=256 ----
    {
        const u16* pA = Ab + (size_t)(row0 + wy * 16 + n) * 256 + q * 8;
        const u16* pB = W1t + (size_t)(wx * 64 + n) * 256 + q * 8;

        f32x4 acc[4];
#pragma unroll
        for (int j = 0; j < 4; j++) acc[j] = f32x4{0.f, 0.f, 0.f, 0.f};

#pragma unroll
        for (int kk = 0; kk < 256; kk += 32) {
            bf16x8 a0 = *(const bf16x8*)(pA + kk);
            bf16x8 b0 = *(const bf16x8*)(pB + kk);
            bf16x8 b1f = *(const bf16x8*)(pB + 16 * 256 + kk);
            bf16x8 b2f = *(const bf16x8*)(pB + 32 * 256 + kk);
            bf16x8 b3f = *(const bf16x8*)(pB + 48 * 256 + kk);
            acc[0] = __builtin_amdgcn_mfma_f32_16x16x32_bf16(a0, b0,  acc[0], 0, 0, 0);
            acc[1] = __builtin_amdgcn_mfma_f32_16x16x32_bf16(a0, b1f, acc[1], 0, 0, 0);
            acc[2] = __builtin_amdgcn_mfma_f32_16x16x32_bf16(a0, b2f, acc[2], 0, 0, 0);
            acc[3] = __builtin_amdgcn_mfma_f32_16x16x32_bf16(a0, b3f, acc[3], 0, 0, 0);
        }

#pragma unroll
        for (int ni = 0; ni < 4; ni++) {
            const int rl = wy * 16 + q * 4;
            const int c = wx * 64 + ni * 16 + n;
#pragma unroll
            for (int r = 0; r < 4; r++) {
                float v = acc[ni][r] + b1[c];
                Hs[rl + r][c] = f2bf(fmaxf(v, 0.f));
            }
        }
    }
    __syncthreads();

    // ---- phase 2: out tile = Hs @ W2t + b2, K=128 ----
    {
        const u16* pB = W2t + (size_t)(wx * 64 + n) * 128 + q * 8;

        f32x4 acc[4];
#pragma unroll
        for (int j = 0; j < 4; j++) acc[j] = f32x4{0.f, 0.f, 0.f, 0.f};

#pragma unroll
        for (int kk = 0; kk < 128; kk += 32) {
            bf16x8 a0 = *(const bf16x8*)&Hs[wy * 16 + n][kk + q * 8];
            bf16x8 b0 = *(const bf16x8*)(pB + kk);
            bf16x8 b1f = *(const bf16x8*)(pB + 16 * 128 + kk);
            bf16x8 b2f = *(const bf16x8*)(pB + 32 * 128 + kk);
            bf16x8 b3f = *(const bf16x8*)(pB + 48 * 128 + kk);
            acc[0] = __builtin_amdgcn_mfma_f32_16x16x32_bf16(a0, b0,  acc[0], 0, 0, 0);
            acc[1] = __builtin_amdgcn_mfma_f32_16x16x32_bf16(a0, b1f, acc[1], 0, 0, 0);
            acc[2] = __builtin_amdgcn_mfma_f32_16x16x32_bf16(a0, b2f, acc[2], 0, 0, 0);
            acc[3] = __builtin_amdgcn_mfma_f32_16x16x32_bf16(a0, b3f, acc[3], 0, 0, 0);
        }

#pragma unroll
        for (int ni = 0; ni < 4; ni++) {
            const int rbase = row0 + wy * 16 + q * 4;
            const int c = wx * 64 + ni * 16 + n;
#pragma unroll
            for (int r = 0; r < 4; r++) {
                const int rr = rbase + r;
                if (rr >= Mstore) continue;
                out[(size_t)rr * 128 + c] = acc[ni][r] + b2[c];
            }
        }
    }
}

extern "C" void kernel_launch(void* const* d_in, const int* in_sizes, int n_in,
                              void* d_out, int out_size, void* d_ws, size_t ws_size,
                              hipStream_t stream) {
    const float* z    = (const float*)d_in[0];
    const float* ew   = (const float*)d_in[1];
    const int*   esrc = (const int*)d_in[2];
    const int*   edst = (const int*)d_in[3];
    const float* Wm   = (const float*)d_in[4];
    const float* bm   = (const float*)d_in[5];
    const float* W1   = (const float*)d_in[6];
    const float* b1   = (const float*)d_in[7];
    const float* W2   = (const float*)d_in[8];
    const float* b2   = (const float*)d_in[9];
    float* out = (float*)d_out;

    const int N  = in_sizes[0] / HID;          // 50000
    const int E  = in_sizes[1];                // 800000
    const int Mp = ((N + 63) / 64) * 64;       // 50048
    const int nbk = (N + 511) / 512;           // 98 buckets

    // workspace layout
    char* w = (char*)d_ws;
    u16*  Ab      = (u16*)w;      w += (size_t)Mp * 256 * 2;   // [zb | aggb]
    u16*  Pb      = (u16*)w;      w += (size_t)Mp * 256 * 2;   // [zWd | zWs]; tmp aliases
    u16*  Wt      = (u16*)w;      w += (size_t)81920 * 2;
    int*  offsets = (int*)w;      w += (size_t)(N + 64) * 4;
    int*  bhist   = (int*)w;      w += 128 * 4;
    int*  brun    = (int*)w;      w += 128 * 4;
    unsigned* s_ew = (unsigned*)w; w += (size_t)E * 4;

    u64* tmp = (u64*)Pb;   // 6.4 MB, consumed by bucket_sort before gemm_P writes Pb

    const int bz = (Mp * 32 + 255) / 256;      // z-cast blocks
    const int bw = (81920 + 255) / 256;        // weight blocks
    const int bh = (E + 4095) / 4096;          // coarse-hist blocks

    hipMemsetAsync(bhist, 0, 256 * sizeof(int), stream);   // bhist + brun
    prep_hist<<<bz + bw + bh, 256, 0, stream>>>(z, Wm, W1, W2, edst, Ab, Wt, bhist,
                                                N, Mp, E, bz, bw, nbk);
    bucket_scatter<<<(E + 4095) / 4096, 256, 0, stream>>>(esrc, edst, ew, bhist, brun,
                                                          tmp, E, nbk);
    bucket_sort<<<nbk, 256, 0, stream>>>(tmp, bhist, offsets, s_ew, N, E, nbk);

    gemm_P<<<Mp / 64, 256, 0, stream>>>(Ab, Wt, Pb, Mp);
    aggregate_kernel<<<(Mp + 3) / 4, 256, 0, stream>>>(Pb, bm, Wm + 256 * 128,
                                                       offsets, s_ew, Ab, N, Mp);
    gemm_HO<<<(Mp + 31) / 32, 256, 0, stream>>>(Ab, Wt + 32768, b1, Wt + 65536, b2, out, N);
}

// Round 9
// 232.173 us; speedup vs baseline: 2.8494x; 1.0848x over previous
//
#include <hip/hip_runtime.h>
#include <hip/hip_bf16.h>

#define HID 128

typedef short bf16x8 __attribute__((ext_vector_type(8)));
typedef float f32x4  __attribute__((ext_vector_type(4)));
typedef unsigned short u16;
typedef unsigned long long u64;

__device__ __forceinline__ u16 f2bf(float f) {
    __hip_bfloat16 h = __float2bfloat16(f);
    return *reinterpret_cast<u16*>(&h);
}
__device__ __forceinline__ float bf2f(u16 x) {
    unsigned u = ((unsigned)x) << 16;
    return __uint_as_float(u);
}
// record: dst(17b)<<31 | src(16b)<<15 | wq(15b); low 31 bits = final s_ew record
__device__ __forceinline__ u64 pack_rec(int dst, int src, float w) {
    int wq = (int)fmaf(w, 32768.f, 0.5f);
    wq = wq > 32767 ? 32767 : wq;
    return ((u64)(unsigned)dst << 31) | ((unsigned)src << 15) | (unsigned)wq;
}

// Wt layout (u16): [0,32768) Wds^T (256 rows x 128k: Wd^T then Ws^T)
//                  [32768,65536) W1^T (128 rows x 256k)
//                  [65536,81920) W2^T (128 rows x 128k)

// ---------- fused prep (z-cast + weight transpose/cast) + COARSE histogram ----------
__global__ __launch_bounds__(256)
void prep_hist(const float* __restrict__ z, const float* __restrict__ Wm,
               const float* __restrict__ W1, const float* __restrict__ W2,
               const int* __restrict__ edst,
               u16* __restrict__ Ab, u16* __restrict__ Wt, int* __restrict__ bhist,
               int N, int Mp, int E, int bz, int bw, int nbk)
{
    __shared__ int lh[128];
    const int b = blockIdx.x;
    const int t = threadIdx.x;
    if (b < bz) {
        const int idx4 = (b * 256 + t) * 4;
        if (idx4 >= Mp * 128) return;
        const int row = idx4 >> 7, col = idx4 & 127;
        ushort4 u;
        if (row < N) {
            const float4 v = *(const float4*)&z[(size_t)row * 128 + col];
            u.x = f2bf(v.x); u.y = f2bf(v.y); u.z = f2bf(v.z); u.w = f2bf(v.w);
        } else { u.x = 0; u.y = 0; u.z = 0; u.w = 0; }
        *(ushort4*)&Ab[(size_t)row * 256 + col] = u;
    } else if (b < bz + bw) {
        const int idx = (b - bz) * 256 + t;
        if (idx >= 81920) return;
        float v;
        if (idx < 32768) {
            const int nn = idx >> 7, k = idx & 127;
            v = (nn < 128) ? Wm[k * 128 + nn] : Wm[(128 + k) * 128 + (nn - 128)];
        } else if (idx < 65536) {
            const int j = idx - 32768, n = j >> 8, k = j & 255;
            v = W1[k * 128 + n];
        } else {
            const int j = idx - 65536, n = j >> 7, k = j & 127;
            v = W2[k * 128 + n];
        }
        Wt[idx] = f2bf(v);
    } else {
        // coarse histogram: 4096 edges/block, LDS-reduced
        if (t < 128) lh[t] = 0;
        __syncthreads();
        const int e0 = (b - bz - bw) * 4096;
        const int eend = min(e0 + 4096, E);
        for (int e = e0 + t; e < eend; e += 256)
            atomicAdd(&lh[edst[e] >> 9], 1);
        __syncthreads();
        if (t < nbk && lh[t] > 0) atomicAdd(&bhist[t], lh[t]);
    }
}

// ---------- pass 1: scatter u64 records into bucket-major order ----------
__global__ __launch_bounds__(256)
void bucket_scatter(const int* __restrict__ esrc, const int* __restrict__ edst,
                    const float* __restrict__ ew,
                    const int* __restrict__ bhist, int* __restrict__ brun,
                    u64* __restrict__ tmp, int E, int nbk)
{
    __shared__ int cnt[128];
    __shared__ int rbase[128];
    __shared__ int bbase[128];
    const int t = threadIdx.x;
    const int e0 = blockIdx.x * 4096;
    const int eend = min(e0 + 4096, E);

    if (t < 128) cnt[t] = 0;
    if (t == 0) {                       // serial 98-prefix: cheap, block-local
        int run = 0;
        for (int i = 0; i < nbk; i++) { bbase[i] = run; run += bhist[i]; }
    }
    __syncthreads();

    if (eend - e0 == 4096) {
        int myb[16]; u64 myrec[16];
#pragma unroll
        for (int i = 0; i < 16; i++) {
            const int e = e0 + t + i * 256;
            const int d = edst[e];
            myb[i] = d >> 9;
            myrec[i] = pack_rec(d, esrc[e], ew[e]);
            atomicAdd(&cnt[myb[i]], 1);
        }
        __syncthreads();
        if (t < nbk && cnt[t] > 0) rbase[t] = bbase[t] + atomicAdd(&brun[t], cnt[t]);
        __syncthreads();
        if (t < 128) cnt[t] = 0;
        __syncthreads();
#pragma unroll
        for (int i = 0; i < 16; i++) {
            const int r = atomicAdd(&cnt[myb[i]], 1);
            tmp[(size_t)rbase[myb[i]] + r] = myrec[i];
        }
    } else {
        for (int e = e0 + t; e < eend; e += 256)
            atomicAdd(&cnt[edst[e] >> 9], 1);
        __syncthreads();
        if (t < nbk && cnt[t] > 0) rbase[t] = bbase[t] + atomicAdd(&brun[t], cnt[t]);
        __syncthreads();
        if (t < 128) cnt[t] = 0;
        __syncthreads();
        for (int e = e0 + t; e < eend; e += 256) {
            const int d = edst[e];
            const int bk = d >> 9;
            const int r = atomicAdd(&cnt[bk], 1);
            tmp[(size_t)rbase[bk] + r] = pack_rec(d, esrc[e], ew[e]);
        }
    }
}

// ---------- pass 2: within-bucket degree count + scan + counting sort ----------
__global__ __launch_bounds__(256)
void bucket_sort(const u64* __restrict__ tmp, const int* __restrict__ bhist,
                 int* __restrict__ offsets, unsigned* __restrict__ s_ew,
                 int N, int E, int nbk)
{
    __shared__ int cnt[512];
    __shared__ int cur[512];
    __shared__ int ps[256];
    __shared__ int sh_base[2];
    const int b = blockIdx.x;
    const int t = threadIdx.x;
    const int n0 = b << 9;
    const int nhi = min(512, N - n0);

    if (t == 0) {
        int run = 0;
        for (int i = 0; i < b; i++) run += bhist[i];
        sh_base[0] = run;
        sh_base[1] = run + bhist[b];
    }
    cnt[t] = 0; cnt[t + 256] = 0;
    __syncthreads();
    const int base = sh_base[0];
    const int endp = sh_base[1];

    for (int r = base + t; r < endp; r += 256)
        atomicAdd(&cnt[(int)(tmp[r] >> 31) - n0], 1);
    __syncthreads();

    const int a0 = cnt[2 * t], a1 = cnt[2 * t + 1];
    const int sp = a0 + a1;
    ps[t] = sp;
    __syncthreads();
    for (int off = 1; off < 256; off <<= 1) {
        int add = (t >= off) ? ps[t - off] : 0;
        __syncthreads();
        ps[t] += add;
        __syncthreads();
    }
    const int ex = ps[t] - sp;
    cur[2 * t]     = base + ex;
    cur[2 * t + 1] = base + ex + a0;
    __syncthreads();

    for (int i = t; i < nhi; i += 256) offsets[n0 + i] = cur[i];
    if (t == 0 && n0 + nhi == N) offsets[N] = E;

    for (int r = base + t; r < endp; r += 256) {
        const u64 rec = tmp[r];
        const int local = (int)(rec >> 31) - n0;
        const int pos = atomicAdd(&cur[local], 1);
        s_ew[pos] = (unsigned)(rec & 0x7FFFFFFFu);
    }
}

// ---------- Pb = z @ [Wd | Ws]  (64 rows x 256 cols per block, K=128) ----------
// A tile staged through LDS: K-loop A-reads are ds_read_b128, not global.
__global__ __launch_bounds__(256)
void gemm_P(const u16* __restrict__ Ab, const u16* __restrict__ Wds_t,
            u16* __restrict__ Pb, int Mp)
{
    __shared__ u16 As[64 * 136];   // 64 rows x 128k, pad 8 -> 2-way banks (free)
    const int row0 = blockIdx.x * 64;
    const int tid = threadIdx.x;
    const int wv = tid >> 6, lane = tid & 63;
    const int wy = wv & 1, wx = wv >> 1;
    const int q = lane >> 4, n = lane & 15;

    // stage A: 64 rows x 256B = 1024 x 16B chunks, 4 per thread (independent)
#pragma unroll
    for (int i = 0; i < 4; i++) {
        const int chunk = i * 256 + tid;
        const int row = chunk >> 4;        // 16 chunks (256B) per row
        const int c8 = chunk & 15;
        *(bf16x8*)&As[row * 136 + c8 * 8] =
            *(const bf16x8*)&Ab[(size_t)(row0 + row) * 256 + c8 * 8];
    }
    __syncthreads();

    const u16* pAl = As + (wy * 32 + n) * 136 + q * 8;
    const u16* pB = Wds_t + (size_t)(wx * 128 + n) * 128 + q * 8;

    f32x4 acc[2][8];
#pragma unroll
    for (int i = 0; i < 2; i++)
#pragma unroll
        for (int j = 0; j < 8; j++) acc[i][j] = f32x4{0.f, 0.f, 0.f, 0.f};

#pragma unroll
    for (int kk = 0; kk < 128; kk += 32) {
        bf16x8 a0 = *(const bf16x8*)(pAl + kk);
        bf16x8 a1 = *(const bf16x8*)(pAl + 16 * 136 + kk);
        bf16x8 bfr[8];
#pragma unroll
        for (int ni = 0; ni < 8; ni++)
            bfr[ni] = *(const bf16x8*)(pB + (size_t)ni * 16 * 128 + kk);
#pragma unroll
        for (int ni = 0; ni < 8; ni++) {
            acc[0][ni] = __builtin_amdgcn_mfma_f32_16x16x32_bf16(a0, bfr[ni], acc[0][ni], 0, 0, 0);
            acc[1][ni] = __builtin_amdgcn_mfma_f32_16x16x32_bf16(a1, bfr[ni], acc[1][ni], 0, 0, 0);
        }
    }

#pragma unroll
    for (int mi = 0; mi < 2; mi++) {
#pragma unroll
        for (int ni = 0; ni < 8; ni++) {
            const int rbase = row0 + wy * 32 + mi * 16 + q * 4;
            const int c = wx * 128 + ni * 16 + n;
#pragma unroll
            for (int r = 0; r < 4; r++)
                Pb[(size_t)(rbase + r) * 256 + c] = f2bf(acc[mi][ni][r]);
        }
    }
}

// ---------- per-node segmented max + finalize -> Ab agg slice ----------
__global__ __launch_bounds__(256)
void aggregate_kernel(const u16* __restrict__ Pb,
                      const float* __restrict__ bm,
                      const float* __restrict__ ww,
                      const int* __restrict__ offsets,
                      const unsigned* __restrict__ s_ew,
                      u16* __restrict__ Ab, int N, int Mp)
{
    const int t = threadIdx.x;
    const int lane = t & 63;
    const int nd = blockIdx.x * 4 + (t >> 6);
    if (nd >= Mp) return;
    const int h0 = lane * 2;
    u16* dst = &Ab[(size_t)nd * 256 + 128 + h0];
    if (nd >= N) { *(ushort2*)dst = make_ushort2(0, 0); return; }

    const int start = offsets[nd];       // wave-uniform
    const int end   = offsets[nd + 1];
    const float ww0 = ww[h0], ww1 = ww[h0 + 1];
    const float kq = 1.f / 32768.f;
    float m0 = -INFINITY, m1 = -INFINITY;

    int e = start;
    for (; e + 3 < end; e += 4) {
        const unsigned u0 = s_ew[e],     u1 = s_ew[e + 1];
        const unsigned u2 = s_ew[e + 2], u3 = s_ew[e + 3];
        const float w0 = (float)(u0 & 32767u) * kq;
        const float w1 = (float)(u1 & 32767u) * kq;
        const float w2 = (float)(u2 & 32767u) * kq;
        const float w3 = (float)(u3 & 32767u) * kq;
        const ushort2 z0 = *(const ushort2*)&Pb[(size_t)(u0 >> 15) * 256 + 128 + h0];
        const ushort2 z1 = *(const ushort2*)&Pb[(size_t)(u1 >> 15) * 256 + 128 + h0];
        const ushort2 z2 = *(const ushort2*)&Pb[(size_t)(u2 >> 15) * 256 + 128 + h0];
        const ushort2 z3 = *(const ushort2*)&Pb[(size_t)(u3 >> 15) * 256 + 128 + h0];
        const float a0 = fmaf(w0, ww0, bf2f(z0.x)), c0 = fmaf(w0, ww1, bf2f(z0.y));
        const float a1 = fmaf(w1, ww0, bf2f(z1.x)), c1 = fmaf(w1, ww1, bf2f(z1.y));
        const float a2 = fmaf(w2, ww0, bf2f(z2.x)), c2 = fmaf(w2, ww1, bf2f(z2.y));
        const float a3 = fmaf(w3, ww0, bf2f(z3.x)), c3 = fmaf(w3, ww1, bf2f(z3.y));
        m0 = fmaxf(m0, fmaxf(fmaxf(a0, a1), fmaxf(a2, a3)));
        m1 = fmaxf(m1, fmaxf(fmaxf(c0, c1), fmaxf(c2, c3)));
    }
    for (; e < end; e++) {
        const unsigned u0 = s_ew[e];
        const float w0 = (float)(u0 & 32767u) * kq;
        const ushort2 z0 = *(const ushort2*)&Pb[(size_t)(u0 >> 15) * 256 + 128 + h0];
        m0 = fmaxf(m0, fmaf(w0, ww0, bf2f(z0.x)));
        m1 = fmaxf(m1, fmaf(w0, ww1, bf2f(z0.y)));
    }

    ushort2 outv;
    if (end > start) {
        const ushort2 zd = *(const ushort2*)&Pb[(size_t)nd * 256 + h0];
        outv.x = f2bf(bf2f(zd.x) + bm[h0]     + m0);
        outv.y = f2bf(bf2f(zd.y) + bm[h0 + 1] + m1);
    } else { outv.x = 0; outv.y = 0; }
    *(ushort2*)dst = outv;
}

// ---------- fused: H = relu([z|agg]@W1+b1) (K=256) -> LDS -> out = H@W2+b2 ----------
// 64-row tiles; A staged through LDS; LDS reused for the H tile (barrier-separated).
__global__ __launch_bounds__(256)
void gemm_HO(const u16* __restrict__ Ab, const u16* __restrict__ W1t,
             const float* __restrict__ b1, const u16* __restrict__ W2t,
             const float* __restrict__ b2, float* __restrict__ out, int Mstore)
{
    __shared__ u16 smem[64 * 264];   // phase1: As 64x(256+8); phase2: Hs 64x136

    const int row0 = blockIdx.x * 64;
    const int tid = threadIdx.x;
    const int wv = tid >> 6, lane = tid & 63;
    const int wy = wv & 1, wx = wv >> 1;
    const int q = lane >> 4, n = lane & 15;

    // stage A: 64 rows x 512B = 2048 x 16B chunks, 8 per thread (independent)
#pragma unroll
    for (int i = 0; i < 8; i++) {
        const int chunk = i * 256 + tid;
        const int row = chunk >> 5;        // 32 chunks (512B) per row
        const int c8 = chunk & 31;
        *(bf16x8*)&smem[row * 264 + c8 * 8] =
            *(const bf16x8*)&Ab[(size_t)(row0 + row) * 256 + c8 * 8];
    }
    __syncthreads();

    f32x4 acc[2][4];

    // ---- phase 1: H tile (64 x 128), K=256, A from LDS ----
    {
        const u16* pAl = smem + (wy * 32 + n) * 264 + q * 8;
        const u16* pB = W1t + (size_t)(wx * 64 + n) * 256 + q * 8;

#pragma unroll
        for (int i = 0; i < 2; i++)
#pragma unroll
            for (int j = 0; j < 4; j++) acc[i][j] = f32x4{0.f, 0.f, 0.f, 0.f};

#pragma unroll
        for (int kk = 0; kk < 256; kk += 32) {
            bf16x8 b0 = *(const bf16x8*)(pB + kk);
            bf16x8 b1f = *(const bf16x8*)(pB + 16 * 256 + kk);
            bf16x8 b2f = *(const bf16x8*)(pB + 32 * 256 + kk);
            bf16x8 b3f = *(const bf16x8*)(pB + 48 * 256 + kk);
            bf16x8 a0 = *(const bf16x8*)(pAl + kk);
            bf16x8 a1 = *(const bf16x8*)(pAl + 16 * 264 + kk);
            acc[0][0] = __builtin_amdgcn_mfma_f32_16x16x32_bf16(a0, b0,  acc[0][0], 0, 0, 0);
            acc[0][1] = __builtin_amdgcn_mfma_f32_16x16x32_bf16(a0, b1f, acc[0][1], 0, 0, 0);
            acc[0][2] = __builtin_amdgcn_mfma_f32_16x16x32_bf16(a0, b2f, acc[0][2], 0, 0, 0);
            acc[0][3] = __builtin_amdgcn_mfma_f32_16x16x32_bf16(a0, b3f, acc[0][3], 0, 0, 0);
            acc[1][0] = __builtin_amdgcn_mfma_f32_16x16x32_bf16(a1, b0,  acc[1][0], 0, 0, 0);
            acc[1][1] = __builtin_amdgcn_mfma_f32_16x16x32_bf16(a1, b1f, acc[1][1], 0, 0, 0);
            acc[1][2] = __builtin_amdgcn_mfma_f32_16x16x32_bf16(a1, b2f, acc[1][2], 0, 0, 0);
            acc[1][3] = __builtin_amdgcn_mfma_f32_16x16x32_bf16(a1, b3f, acc[1][3], 0, 0, 0);
        }
    }
    __syncthreads();   // all As reads done before Hs overwrites smem

    // write H tile (bf16) into smem as Hs[64][136]
#pragma unroll
    for (int mi = 0; mi < 2; mi++) {
#pragma unroll
        for (int ni = 0; ni < 4; ni++) {
            const int rl = wy * 32 + mi * 16 + q * 4;
            const int c = wx * 64 + ni * 16 + n;
#pragma unroll
            for (int r = 0; r < 4; r++) {
                float v = acc[mi][ni][r] + b1[c];
                smem[(rl + r) * 136 + c] = f2bf(fmaxf(v, 0.f));
            }
        }
    }
    __syncthreads();

    // ---- phase 2: out tile = Hs @ W2t + b2, K=128 ----
    {
        const u16* pB = W2t + (size_t)(wx * 64 + n) * 128 + q * 8;
        const u16* pHl = smem + (wy * 32 + n) * 136 + q * 8;

#pragma unroll
        for (int i = 0; i < 2; i++)
#pragma unroll
            for (int j = 0; j < 4; j++) acc[i][j] = f32x4{0.f, 0.f, 0.f, 0.f};

#pragma unroll
        for (int kk = 0; kk < 128; kk += 32) {
            bf16x8 b0 = *(const bf16x8*)(pB + kk);
            bf16x8 b1f = *(const bf16x8*)(pB + 16 * 128 + kk);
            bf16x8 b2f = *(const bf16x8*)(pB + 32 * 128 + kk);
            bf16x8 b3f = *(const bf16x8*)(pB + 48 * 128 + kk);
            bf16x8 a0 = *(const bf16x8*)(pHl + kk);
            bf16x8 a1 = *(const bf16x8*)(pHl + 16 * 136 + kk);
            acc[0][0] = __builtin_amdgcn_mfma_f32_16x16x32_bf16(a0, b0,  acc[0][0], 0, 0, 0);
            acc[0][1] = __builtin_amdgcn_mfma_f32_16x16x32_bf16(a0, b1f, acc[0][1], 0, 0, 0);
            acc[0][2] = __builtin_amdgcn_mfma_f32_16x16x32_bf16(a0, b2f, acc[0][2], 0, 0, 0);
            acc[0][3] = __builtin_amdgcn_mfma_f32_16x16x32_bf16(a0, b3f, acc[0][3], 0, 0, 0);
            acc[1][0] = __builtin_amdgcn_mfma_f32_16x16x32_bf16(a1, b0,  acc[1][0], 0, 0, 0);
            acc[1][1] = __builtin_amdgcn_mfma_f32_16x16x32_bf16(a1, b1f, acc[1][1], 0, 0, 0);
            acc[1][2] = __builtin_amdgcn_mfma_f32_16x16x32_bf16(a1, b2f, acc[1][2], 0, 0, 0);
            acc[1][3] = __builtin_amdgcn_mfma_f32_16x16x32_bf16(a1, b3f, acc[1][3], 0, 0, 0);
        }

#pragma unroll
        for (int mi = 0; mi < 2; mi++) {
#pragma unroll
            for (int ni = 0; ni < 4; ni++) {
                const int rbase = row0 + wy * 32 + mi * 16 + q * 4;
                const int c = wx * 64 + ni * 16 + n;
#pragma unroll
                for (int r = 0; r < 4; r++) {
                    const int rr = rbase + r;
                    if (rr >= Mstore) continue;
                    out[(size_t)rr * 128 + c] = acc[mi][ni][r] + b2[c];
                }
            }
        }
    }
}

extern "C" void kernel_launch(void* const* d_in, const int* in_sizes, int n_in,
                              void* d_out, int out_size, void* d_ws, size_t ws_size,
                              hipStream_t stream) {
    const float* z    = (const float*)d_in[0];
    const float* ew   = (const float*)d_in[1];
    const int*   esrc = (const int*)d_in[2];
    const int*   edst = (const int*)d_in[3];
    const float* Wm   = (const float*)d_in[4];
    const float* bm   = (const float*)d_in[5];
    const float* W1   = (const float*)d_in[6];
    const float* b1   = (const float*)d_in[7];
    const float* W2   = (const float*)d_in[8];
    const float* b2   = (const float*)d_in[9];
    float* out = (float*)d_out;

    const int N  = in_sizes[0] / HID;          // 50000
    const int E  = in_sizes[1];                // 800000
    const int Mp = ((N + 63) / 64) * 64;       // 50048
    const int nbk = (N + 511) / 512;           // 98 buckets

    // workspace layout
    char* w = (char*)d_ws;
    u16*  Ab      = (u16*)w;      w += (size_t)Mp * 256 * 2;   // [zb | aggb]
    u16*  Pb      = (u16*)w;      w += (size_t)Mp * 256 * 2;   // [zWd | zWs]; tmp aliases
    u16*  Wt      = (u16*)w;      w += (size_t)81920 * 2;
    int*  offsets = (int*)w;      w += (size_t)(N + 64) * 4;
    int*  bhist   = (int*)w;      w += 128 * 4;
    int*  brun    = (int*)w;      w += 128 * 4;
    unsigned* s_ew = (unsigned*)w; w += (size_t)E * 4;

    u64* tmp = (u64*)Pb;   // 6.4 MB, consumed by bucket_sort before gemm_P writes Pb

    const int bz = (Mp * 32 + 255) / 256;      // z-cast blocks
    const int bw = (81920 + 255) / 256;        // weight blocks
    const int bh = (E + 4095) / 4096;          // coarse-hist blocks

    hipMemsetAsync(bhist, 0, 256 * sizeof(int), stream);   // bhist + brun
    prep_hist<<<bz + bw + bh, 256, 0, stream>>>(z, Wm, W1, W2, edst, Ab, Wt, bhist,
                                                N, Mp, E, bz, bw, nbk);
    bucket_scatter<<<(E + 4095) / 4096, 256, 0, stream>>>(esrc, edst, ew, bhist, brun,
                                                          tmp, E, nbk);
    bucket_sort<<<nbk, 256, 0, stream>>>(tmp, bhist, offsets, s_ew, N, E, nbk);

    gemm_P<<<Mp / 64, 256, 0, stream>>>(Ab, Wt, Pb, Mp);
    aggregate_kernel<<<(Mp + 3) / 4, 256, 0, stream>>>(Pb, bm, Wm + 256 * 128,
                                                       offsets, s_ew, Ab, N, Mp);
    gemm_HO<<<Mp / 64, 256, 0, stream>>>(Ab, Wt + 32768, b1, Wt + 65536, b2, out, N);
}

// Round 10
// 220.633 us; speedup vs baseline: 2.9984x; 1.0523x over previous
//
#include <hip/hip_runtime.h>
#include <hip/hip_bf16.h>

#define HID 128

typedef short bf16x8 __attribute__((ext_vector_type(8)));
typedef float f32x4  __attribute__((ext_vector_type(4)));
typedef unsigned short u16;
typedef unsigned long long u64;

__device__ __forceinline__ u16 f2bf(float f) {
    __hip_bfloat16 h = __float2bfloat16(f);
    return *reinterpret_cast<u16*>(&h);
}
__device__ __forceinline__ float bf2f(u16 x) {
    unsigned u = ((unsigned)x) << 16;
    return __uint_as_float(u);
}
// record: dst(17b)<<31 | src(16b)<<15 | wq(15b); low 31 bits = final s_ew record
__device__ __forceinline__ u64 pack_rec(int dst, int src, float w) {
    int wq = (int)fmaf(w, 32768.f, 0.5f);
    wq = wq > 32767 ? 32767 : wq;
    return ((u64)(unsigned)dst << 31) | ((unsigned)src << 15) | (unsigned)wq;
}

// Wt layout (u16): [0,32768) Wds^T (256 rows x 128k: Wd^T then Ws^T)
//                  [32768,65536) W1^T (128 rows x 256k)
//                  [65536,81920) W2^T (128 rows x 128k)

// ---------- fused prep (z-cast + weight transpose/cast) + COARSE histogram ----------
__global__ __launch_bounds__(256)
void prep_hist(const float* __restrict__ z, const float* __restrict__ Wm,
               const float* __restrict__ W1, const float* __restrict__ W2,
               const int* __restrict__ edst,
               u16* __restrict__ Ab, u16* __restrict__ Wt, int* __restrict__ bhist,
               int N, int Mp, int E, int bz, int bw, int nbk)
{
    __shared__ int lh[256];
    const int b = blockIdx.x;
    const int t = threadIdx.x;
    if (b < bz) {
        const int idx4 = (b * 256 + t) * 4;
        if (idx4 >= Mp * 128) return;
        const int row = idx4 >> 7, col = idx4 & 127;
        ushort4 u;
        if (row < N) {
            const float4 v = *(const float4*)&z[(size_t)row * 128 + col];
            u.x = f2bf(v.x); u.y = f2bf(v.y); u.z = f2bf(v.z); u.w = f2bf(v.w);
        } else { u.x = 0; u.y = 0; u.z = 0; u.w = 0; }
        *(ushort4*)&Ab[(size_t)row * 256 + col] = u;
    } else if (b < bz + bw) {
        const int idx = (b - bz) * 256 + t;
        if (idx >= 81920) return;
        float v;
        if (idx < 32768) {
            const int nn = idx >> 7, k = idx & 127;
            v = (nn < 128) ? Wm[k * 128 + nn] : Wm[(128 + k) * 128 + (nn - 128)];
        } else if (idx < 65536) {
            const int j = idx - 32768, n = j >> 8, k = j & 255;
            v = W1[k * 128 + n];
        } else {
            const int j = idx - 65536, n = j >> 7, k = j & 127;
            v = W2[k * 128 + n];
        }
        Wt[idx] = f2bf(v);
    } else {
        // coarse histogram (256-node buckets): 4096 edges/block, LDS-reduced
        lh[t] = 0;
        __syncthreads();
        const int e0 = (b - bz - bw) * 4096;
        const int eend = min(e0 + 4096, E);
        for (int e = e0 + t; e < eend; e += 256)
            atomicAdd(&lh[edst[e] >> 8], 1);
        __syncthreads();
        if (t < nbk && lh[t] > 0) atomicAdd(&bhist[t], lh[t]);
    }
}

// ---------- fused: bucket scatter (pass 1)  ||  gemm_P  (independent stages) ----------
__global__ __launch_bounds__(256)
void scatter_gemmP(const int* __restrict__ esrc, const int* __restrict__ edst,
                   const float* __restrict__ ew,
                   const int* __restrict__ bhist, int* __restrict__ brun,
                   u64* __restrict__ tmp, int E, int nbk, int nsc,
                   const u16* __restrict__ Ab, const u16* __restrict__ Wds_t,
                   u16* __restrict__ Pb, int Mp)
{
    __shared__ int cnt[256];
    __shared__ int rbase[256];
    __shared__ int bbase[256];
    __shared__ u16 As[64 * 136];
    const int t = threadIdx.x;

    if (blockIdx.x < nsc) {
        // ---- scatter: u64 records into bucket-major order, dense runs ----
        const int e0 = blockIdx.x * 4096;
        const int eend = min(e0 + 4096, E);

        cnt[t] = 0;
        if (t == 0) {                   // serial nbk-prefix: block-local, cached
            int run = 0;
            for (int i = 0; i < nbk; i++) { bbase[i] = run; run += bhist[i]; }
        }
        __syncthreads();

        if (eend - e0 == 4096) {
            int myb[16]; u64 myrec[16];
#pragma unroll
            for (int i = 0; i < 16; i++) {
                const int e = e0 + t + i * 256;
                const int d = edst[e];
                myb[i] = d >> 8;
                myrec[i] = pack_rec(d, esrc[e], ew[e]);
                atomicAdd(&cnt[myb[i]], 1);
            }
            __syncthreads();
            if (t < nbk && cnt[t] > 0) rbase[t] = bbase[t] + atomicAdd(&brun[t], cnt[t]);
            __syncthreads();
            cnt[t] = 0;
            __syncthreads();
#pragma unroll
            for (int i = 0; i < 16; i++) {
                const int r = atomicAdd(&cnt[myb[i]], 1);
                tmp[(size_t)rbase[myb[i]] + r] = myrec[i];
            }
        } else {
            for (int e = e0 + t; e < eend; e += 256)
                atomicAdd(&cnt[edst[e] >> 8], 1);
            __syncthreads();
            if (t < nbk && cnt[t] > 0) rbase[t] = bbase[t] + atomicAdd(&brun[t], cnt[t]);
            __syncthreads();
            cnt[t] = 0;
            __syncthreads();
            for (int e = e0 + t; e < eend; e += 256) {
                const int d = edst[e];
                const int bk = d >> 8;
                const int r = atomicAdd(&cnt[bk], 1);
                tmp[(size_t)rbase[bk] + r] = pack_rec(d, esrc[e], ew[e]);
            }
        }
    } else {
        // ---- gemm_P: Pb = z @ [Wd | Ws], 64 rows x 256 cols, A via LDS ----
        const int row0 = (blockIdx.x - nsc) * 64;
        const int wv = t >> 6, lane = t & 63;
        const int wy = wv & 1, wx = wv >> 1;
        const int q = lane >> 4, n = lane & 15;

#pragma unroll
        for (int i = 0; i < 4; i++) {
            const int chunk = i * 256 + t;
            const int row = chunk >> 4;
            const int c8 = chunk & 15;
            *(bf16x8*)&As[row * 136 + c8 * 8] =
                *(const bf16x8*)&Ab[(size_t)(row0 + row) * 256 + c8 * 8];
        }
        __syncthreads();

        const u16* pAl = As + (wy * 32 + n) * 136 + q * 8;
        const u16* pB = Wds_t + (size_t)(wx * 128 + n) * 128 + q * 8;

        f32x4 acc[2][8];
#pragma unroll
        for (int i = 0; i < 2; i++)
#pragma unroll
            for (int j = 0; j < 8; j++) acc[i][j] = f32x4{0.f, 0.f, 0.f, 0.f};

#pragma unroll
        for (int kk = 0; kk < 128; kk += 32) {
            bf16x8 a0 = *(const bf16x8*)(pAl + kk);
            bf16x8 a1 = *(const bf16x8*)(pAl + 16 * 136 + kk);
            bf16x8 bfr[8];
#pragma unroll
            for (int ni = 0; ni < 8; ni++)
                bfr[ni] = *(const bf16x8*)(pB + (size_t)ni * 16 * 128 + kk);
#pragma unroll
            for (int ni = 0; ni < 8; ni++) {
                acc[0][ni] = __builtin_amdgcn_mfma_f32_16x16x32_bf16(a0, bfr[ni], acc[0][ni], 0, 0, 0);
                acc[1][ni] = __builtin_amdgcn_mfma_f32_16x16x32_bf16(a1, bfr[ni], acc[1][ni], 0, 0, 0);
            }
        }

#pragma unroll
        for (int mi = 0; mi < 2; mi++) {
#pragma unroll
            for (int ni = 0; ni < 8; ni++) {
                const int rbase2 = row0 + wy * 32 + mi * 16 + q * 4;
                const int c = wx * 128 + ni * 16 + n;
#pragma unroll
                for (int r = 0; r < 4; r++)
                    Pb[(size_t)(rbase2 + r) * 256 + c] = f2bf(acc[mi][ni][r]);
            }
        }
    }
}

// ---------- pass 2: within-bucket degree count + scan + counting sort ----------
// one block per 256-node bucket; writes CSR offsets AND the final sorted stream.
__global__ __launch_bounds__(256)
void bucket_sort(const u64* __restrict__ tmp, const int* __restrict__ bhist,
                 int* __restrict__ offsets, unsigned* __restrict__ s_ew,
                 int N, int E, int nbk)
{
    __shared__ int cnt[256];
    __shared__ int cur[256];
    __shared__ int ps[256];
    __shared__ int sh_base[2];
    const int b = blockIdx.x;
    const int t = threadIdx.x;
    const int n0 = b << 8;
    const int nhi = min(256, N - n0);

    if (t == 0) {
        int run = 0;
        for (int i = 0; i < b; i++) run += bhist[i];
        sh_base[0] = run;
        sh_base[1] = run + bhist[b];
    }
    cnt[t] = 0;
    __syncthreads();
    const int base = sh_base[0];
    const int endp = sh_base[1];

    for (int r = base + t; r < endp; r += 256)
        atomicAdd(&cnt[(int)(tmp[r] >> 31) - n0], 1);
    __syncthreads();

    const int v = cnt[t];
    ps[t] = v;
    __syncthreads();
    for (int off = 1; off < 256; off <<= 1) {
        int add = (t >= off) ? ps[t - off] : 0;
        __syncthreads();
        ps[t] += add;
        __syncthreads();
    }
    cur[t] = base + ps[t] - v;
    __syncthreads();

    if (t < nhi) offsets[n0 + t] = cur[t];
    if (t == 0 && n0 + nhi == N) offsets[N] = E;

    for (int r = base + t; r < endp; r += 256) {
        const u64 rec = tmp[r];
        const int local = (int)(rec >> 31) - n0;
        const int pos = atomicAdd(&cur[local], 1);
        s_ew[pos] = (unsigned)(rec & 0x7FFFFFFFu);
    }
}

// ---------- per-node segmented max + finalize -> Ab agg slice (8-deep unroll) ----------
__global__ __launch_bounds__(256)
void aggregate_kernel(const u16* __restrict__ Pb,
                      const float* __restrict__ bm,
                      const float* __restrict__ ww,
                      const int* __restrict__ offsets,
                      const unsigned* __restrict__ s_ew,
                      u16* __restrict__ Ab, int N, int Mp)
{
    const int t = threadIdx.x;
    const int lane = t & 63;
    const int nd = blockIdx.x * 4 + (t >> 6);
    if (nd >= Mp) return;
    const int h0 = lane * 2;
    u16* dst = &Ab[(size_t)nd * 256 + 128 + h0];
    if (nd >= N) { *(ushort2*)dst = make_ushort2(0, 0); return; }

    const int start = offsets[nd];       // wave-uniform
    const int end   = offsets[nd + 1];
    const float ww0 = ww[h0], ww1 = ww[h0 + 1];
    const float kq = 1.f / 32768.f;
    float m0 = -INFINITY, m1 = -INFINITY;

    int e = start;
    for (; e + 7 < end; e += 8) {
        unsigned u[8]; ushort2 zz[8];
#pragma unroll
        for (int i = 0; i < 8; i++) u[i] = s_ew[e + i];
#pragma unroll
        for (int i = 0; i < 8; i++)
            zz[i] = *(const ushort2*)&Pb[(size_t)(u[i] >> 15) * 256 + 128 + h0];
        float ma[8], mb[8];
#pragma unroll
        for (int i = 0; i < 8; i++) {
            const float wq = (float)(u[i] & 32767u) * kq;
            ma[i] = fmaf(wq, ww0, bf2f(zz[i].x));
            mb[i] = fmaf(wq, ww1, bf2f(zz[i].y));
        }
        m0 = fmaxf(m0, fmaxf(fmaxf(fmaxf(ma[0], ma[1]), fmaxf(ma[2], ma[3])),
                             fmaxf(fmaxf(ma[4], ma[5]), fmaxf(ma[6], ma[7]))));
        m1 = fmaxf(m1, fmaxf(fmaxf(fmaxf(mb[0], mb[1]), fmaxf(mb[2], mb[3])),
                             fmaxf(fmaxf(mb[4], mb[5]), fmaxf(mb[6], mb[7]))));
    }
    for (; e < end; e++) {
        const unsigned u0 = s_ew[e];
        const float w0 = (float)(u0 & 32767u) * kq;
        const ushort2 z0 = *(const ushort2*)&Pb[(size_t)(u0 >> 15) * 256 + 128 + h0];
        m0 = fmaxf(m0, fmaf(w0, ww0, bf2f(z0.x)));
        m1 = fmaxf(m1, fmaf(w0, ww1, bf2f(z0.y)));
    }

    ushort2 outv;
    if (end > start) {
        const ushort2 zd = *(const ushort2*)&Pb[(size_t)nd * 256 + h0];
        outv.x = f2bf(bf2f(zd.x) + bm[h0]     + m0);
        outv.y = f2bf(bf2f(zd.y) + bm[h0 + 1] + m1);
    } else { outv.x = 0; outv.y = 0; }
    *(ushort2*)dst = outv;
}

// ---------- fused: H = relu([z|agg]@W1+b1) (K=256) -> LDS -> out = H@W2+b2 ----------
__global__ __launch_bounds__(256)
void gemm_HO(const u16* __restrict__ Ab, const u16* __restrict__ W1t,
             const float* __restrict__ b1, const u16* __restrict__ W2t,
             const float* __restrict__ b2, float* __restrict__ out, int Mstore)
{
    __shared__ u16 smem[64 * 264];   // phase1: As 64x(256+8); phase2: Hs 64x136

    const int row0 = blockIdx.x * 64;
    const int tid = threadIdx.x;
    const int wv = tid >> 6, lane = tid & 63;
    const int wy = wv & 1, wx = wv >> 1;
    const int q = lane >> 4, n = lane & 15;

#pragma unroll
    for (int i = 0; i < 8; i++) {
        const int chunk = i * 256 + tid;
        const int row = chunk >> 5;
        const int c8 = chunk & 31;
        *(bf16x8*)&smem[row * 264 + c8 * 8] =
            *(const bf16x8*)&Ab[(size_t)(row0 + row) * 256 + c8 * 8];
    }
    __syncthreads();

    f32x4 acc[2][4];

    // ---- phase 1: H tile (64 x 128), K=256, A from LDS ----
    {
        const u16* pAl = smem + (wy * 32 + n) * 264 + q * 8;
        const u16* pB = W1t + (size_t)(wx * 64 + n) * 256 + q * 8;

#pragma unroll
        for (int i = 0; i < 2; i++)
#pragma unroll
            for (int j = 0; j < 4; j++) acc[i][j] = f32x4{0.f, 0.f, 0.f, 0.f};

#pragma unroll
        for (int kk = 0; kk < 256; kk += 32) {
            bf16x8 b0 = *(const bf16x8*)(pB + kk);
            bf16x8 b1f = *(const bf16x8*)(pB + 16 * 256 + kk);
            bf16x8 b2f = *(const bf16x8*)(pB + 32 * 256 + kk);
            bf16x8 b3f = *(const bf16x8*)(pB + 48 * 256 + kk);
            bf16x8 a0 = *(const bf16x8*)(pAl + kk);
            bf16x8 a1 = *(const bf16x8*)(pAl + 16 * 264 + kk);
            acc[0][0] = __builtin_amdgcn_mfma_f32_16x16x32_bf16(a0, b0,  acc[0][0], 0, 0, 0);
            acc[0][1] = __builtin_amdgcn_mfma_f32_16x16x32_bf16(a0, b1f, acc[0][1], 0, 0, 0);
            acc[0][2] = __builtin_amdgcn_mfma_f32_16x16x32_bf16(a0, b2f, acc[0][2], 0, 0, 0);
            acc[0][3] = __builtin_amdgcn_mfma_f32_16x16x32_bf16(a0, b3f, acc[0][3], 0, 0, 0);
            acc[1][0] = __builtin_amdgcn_mfma_f32_16x16x32_bf16(a1, b0,  acc[1][0], 0, 0, 0);
            acc[1][1] = __builtin_amdgcn_mfma_f32_16x16x32_bf16(a1, b1f, acc[1][1], 0, 0, 0);
            acc[1][2] = __builtin_amdgcn_mfma_f32_16x16x32_bf16(a1, b2f, acc[1][2], 0, 0, 0);
            acc[1][3] = __builtin_amdgcn_mfma_f32_16x16x32_bf16(a1, b3f, acc[1][3], 0, 0, 0);
        }
    }
    __syncthreads();

#pragma unroll
    for (int mi = 0; mi < 2; mi++) {
#pragma unroll
        for (int ni = 0; ni < 4; ni++) {
            const int rl = wy * 32 + mi * 16 + q * 4;
            const int c = wx * 64 + ni * 16 + n;
#pragma unroll
            for (int r = 0; r < 4; r++) {
                float v = acc[mi][ni][r] + b1[c];
                smem[(rl + r) * 136 + c] = f2bf(fmaxf(v, 0.f));
            }
        }
    }
    __syncthreads();

    // ---- phase 2: out tile = Hs @ W2t + b2, K=128 ----
    {
        const u16* pB = W2t + (size_t)(wx * 64 + n) * 128 + q * 8;
        const u16* pHl = smem + (wy * 32 + n) * 136 + q * 8;

#pragma unroll
        for (int i = 0; i < 2; i++)
#pragma unroll
            for (int j = 0; j < 4; j++) acc[i][j] = f32x4{0.f, 0.f, 0.f, 0.f};

#pragma unroll
        for (int kk = 0; kk < 128; kk += 32) {
            bf16x8 b0 = *(const bf16x8*)(pB + kk);
            bf16x8 b1f = *(const bf16x8*)(pB + 16 * 128 + kk);
            bf16x8 b2f = *(const bf16x8*)(pB + 32 * 128 + kk);
            bf16x8 b3f = *(const bf16x8*)(pB + 48 * 128 + kk);
            bf16x8 a0 = *(const bf16x8*)(pHl + kk);
            bf16x8 a1 = *(const bf16x8*)(pHl + 16 * 136 + kk);
            acc[0][0] = __builtin_amdgcn_mfma_f32_16x16x32_bf16(a0, b0,  acc[0][0], 0, 0, 0);
            acc[0][1] = __builtin_amdgcn_mfma_f32_16x16x32_bf16(a0, b1f, acc[0][1], 0, 0, 0);
            acc[0][2] = __builtin_amdgcn_mfma_f32_16x16x32_bf16(a0, b2f, acc[0][2], 0, 0, 0);
            acc[0][3] = __builtin_amdgcn_mfma_f32_16x16x32_bf16(a0, b3f, acc[0][3], 0, 0, 0);
            acc[1][0] = __builtin_amdgcn_mfma_f32_16x16x32_bf16(a1, b0,  acc[1][0], 0, 0, 0);
            acc[1][1] = __builtin_amdgcn_mfma_f32_16x16x32_bf16(a1, b1f, acc[1][1], 0, 0, 0);
            acc[1][2] = __builtin_amdgcn_mfma_f32_16x16x32_bf16(a1, b2f, acc[1][2], 0, 0, 0);
            acc[1][3] = __builtin_amdgcn_mfma_f32_16x16x32_bf16(a1, b3f, acc[1][3], 0, 0, 0);
        }

#pragma unroll
        for (int mi = 0; mi < 2; mi++) {
#pragma unroll
            for (int ni = 0; ni < 4; ni++) {
                const int rbase = row0 + wy * 32 + mi * 16 + q * 4;
                const int c = wx * 64 + ni * 16 + n;
#pragma unroll
                for (int r = 0; r < 4; r++) {
                    const int rr = rbase + r;
                    if (rr >= Mstore) continue;
                    out[(size_t)rr * 128 + c] = acc[mi][ni][r] + b2[c];
                }
            }
        }
    }
}

extern "C" void kernel_launch(void* const* d_in, const int* in_sizes, int n_in,
                              void* d_out, int out_size, void* d_ws, size_t ws_size,
                              hipStream_t stream) {
    const float* z    = (const float*)d_in[0];
    const float* ew   = (const float*)d_in[1];
    const int*   esrc = (const int*)d_in[2];
    const int*   edst = (const int*)d_in[3];
    const float* Wm   = (const float*)d_in[4];
    const float* bm   = (const float*)d_in[5];
    const float* W1   = (const float*)d_in[6];
    const float* b1   = (const float*)d_in[7];
    const float* W2   = (const float*)d_in[8];
    const float* b2   = (const float*)d_in[9];
    float* out = (float*)d_out;

    const int N  = in_sizes[0] / HID;          // 50000
    const int E  = in_sizes[1];                // 800000
    const int Mp = ((N + 63) / 64) * 64;       // 50048
    const int nbk = (N + 255) / 256;           // 196 buckets (256 nodes each)

    // workspace layout
    char* w = (char*)d_ws;
    u16*  Ab      = (u16*)w;      w += (size_t)Mp * 256 * 2;   // [zb | aggb]
    u16*  Pb      = (u16*)w;      w += (size_t)Mp * 256 * 2;   // [zWd | zWs]
    u16*  Wt      = (u16*)w;      w += (size_t)81920 * 2;
    int*  offsets = (int*)w;      w += (size_t)(N + 64) * 4;
    int*  bhist   = (int*)w;      w += 256 * 4;
    int*  brun    = (int*)w;      w += 256 * 4;
    unsigned* s_ew = (unsigned*)w; w += (size_t)E * 4;
    u64*  tmp     = (u64*)w;      w += (size_t)E * 8;          // un-aliased from Pb

    const int bz = (Mp * 32 + 255) / 256;      // z-cast blocks
    const int bw = (81920 + 255) / 256;        // weight blocks
    const int bh = (E + 4095) / 4096;          // coarse-hist blocks
    const int nsc = (E + 4095) / 4096;         // scatter blocks in fused launch

    hipMemsetAsync(bhist, 0, 512 * sizeof(int), stream);   // bhist + brun
    prep_hist<<<bz + bw + bh, 256, 0, stream>>>(z, Wm, W1, W2, edst, Ab, Wt, bhist,
                                                N, Mp, E, bz, bw, nbk);
    // scatter || gemm_P in one launch (independent stages, MFMA + atomics co-schedule)
    scatter_gemmP<<<nsc + Mp / 64, 256, 0, stream>>>(esrc, edst, ew, bhist, brun,
                                                     tmp, E, nbk, nsc,
                                                     Ab, Wt, Pb, Mp);
    bucket_sort<<<nbk, 256, 0, stream>>>(tmp, bhist, offsets, s_ew, N, E, nbk);
    aggregate_kernel<<<(Mp + 3) / 4, 256, 0, stream>>>(Pb, bm, Wm + 256 * 128,
                                                       offsets, s_ew, Ab, N, Mp);
    gemm_HO<<<Mp / 64, 256, 0, stream>>>(Ab, Wt + 32768, b1, Wt + 65536, b2, out, N);
}